// Round 13
// baseline (1174.904 us; speedup 1.0000x reference)
//
#include <hip/hip_runtime.h>
#include <hip/hip_bf16.h>
#include <hip/hip_fp16.h>

#define Bn  128
#define Ln  256
#define En  300
#define Hn  128
#define Cn  4
#define Dn  256     // 2H
#define G3n 384     // 3H
#define BLn (Bn * Ln)   // 32768

typedef __hip_bfloat16 bf16;
typedef short s16x8 __attribute__((ext_vector_type(8)));
typedef float f32x4 __attribute__((ext_vector_type(4)));
typedef _Float16 h16x2 __attribute__((ext_vector_type(2)));

__device__ __forceinline__ float ldf(const float* p) { return *p; }
__device__ __forceinline__ float ldf(const bf16* p)  { return __bfloat162float(*p); }
__device__ __forceinline__ void stf(float* p, float v) { *p = v; }
__device__ __forceinline__ void stf(bf16* p, float v)  { *p = __float2bfloat16(v); }

__device__ __forceinline__ ushort f2bf(float f) {
    bf16 h = __float2bfloat16(f);
    return *reinterpret_cast<ushort*>(&h);
}
__device__ __forceinline__ float bfu(ushort x) {
    unsigned t = ((unsigned)x) << 16;
    return __builtin_bit_cast(float, t);
}

#if __has_builtin(__builtin_amdgcn_fdot2)
__device__ __forceinline__ float dot2f(h16x2 w, h16x2 h, float c) {
    return __builtin_amdgcn_fdot2(w, h, c, false);
}
#else
__device__ __forceinline__ float dot2f(h16x2 w, h16x2 h, float c) {
    return fmaf((float)w[0], (float)h[0], fmaf((float)w[1], (float)h[1], c));
}
#endif
#define BCH(x) __builtin_bit_cast(h16x2, x)

// uniform lane broadcast on the VALU pipe (not LDS)
__device__ __forceinline__ float rdl(float v, int l) {
    return __builtin_bit_cast(float,
        __builtin_amdgcn_readlane(__builtin_bit_cast(int, v), l));
}

// 16B-or-8B load of 4 values, fp32 or bf16 source
__device__ __forceinline__ float4 ld4f(const float* p) { return *(const float4*)p; }
__device__ __forceinline__ float4 ld4f(const bf16* p) {
    ushort4 u = *(const ushort4*)p;
    return make_float4(bfu(u.x), bfu(u.y), bfu(u.z), bfu(u.w));
}

// ---------------------------------------------------------------------------
// MFMA bf16 GEMM: C[M,N] = A[M,K] * W^T + bias   (W is (N,K) row-major)
//   AT/WTp in {float,bf16}; GATHER: A row m = A[gidx[m]*K ..]
//   SM==1: store C[(m>>8),n,(m&255)]
// ---------------------------------------------------------------------------
template<class AT, class WTp, class OT, bool GATHER, int SM>
__global__ __launch_bounds__(256)
void gemm_mfma(const AT* __restrict__ A, const WTp* __restrict__ W,
               const float* __restrict__ bias, OT* __restrict__ Cout,
               const int* __restrict__ gidx, int M, int N, int K)
{
    __shared__ ushort Asm[128 * 40];
    __shared__ ushort Bsm[128 * 40];
    const int bm = blockIdx.y * 128, bn = blockIdx.x * 128;
    const int tid = threadIdx.x;
    const int lane = tid & 63, w = tid >> 6, wr = w >> 1, wc = w & 1;

    const AT* arow[4];
    const WTp* brow[4];
#pragma unroll
    for (int u = 0; u < 4; ++u) {
        const int idx = tid + u * 256;
        const int m = idx >> 3;
        arow[u] = A + (size_t)(GATHER ? gidx[bm + m] : (bm + m)) * K;
        brow[u] = W + (size_t)(bn + m) * K;
    }

    f32x4 acc[4][4] = {};
    const int nkt = (K + 31) >> 5;
    for (int kt = 0; kt < nkt; ++kt) {
        const int k0 = kt << 5;
#pragma unroll
        for (int u = 0; u < 4; ++u) {
            const int idx = tid + u * 256;
            const int m = idx >> 3, kq = idx & 7;
            const int kb = k0 + kq * 4;
            float4 v, q;
            if (kb + 4 <= K) {
                v = ld4f(arow[u] + kb);
                q = ld4f(brow[u] + kb);
            } else {
                v.x = kb + 0 < K ? ldf(&arow[u][kb + 0]) : 0.f;
                v.y = kb + 1 < K ? ldf(&arow[u][kb + 1]) : 0.f;
                v.z = kb + 2 < K ? ldf(&arow[u][kb + 2]) : 0.f;
                v.w = kb + 3 < K ? ldf(&arow[u][kb + 3]) : 0.f;
                q.x = kb + 0 < K ? ldf(&brow[u][kb + 0]) : 0.f;
                q.y = kb + 1 < K ? ldf(&brow[u][kb + 1]) : 0.f;
                q.z = kb + 2 < K ? ldf(&brow[u][kb + 2]) : 0.f;
                q.w = kb + 3 < K ? ldf(&brow[u][kb + 3]) : 0.f;
            }
            *(ushort4*)&Asm[m * 40 + kq * 4] =
                make_ushort4(f2bf(v.x), f2bf(v.y), f2bf(v.z), f2bf(v.w));
            *(ushort4*)&Bsm[m * 40 + kq * 4] =
                make_ushort4(f2bf(q.x), f2bf(q.y), f2bf(q.z), f2bf(q.w));
        }
        __syncthreads();
        s16x8 af[4], bfr[4];
#pragma unroll
        for (int t = 0; t < 4; ++t) {
            af[t]  = *(const s16x8*)&Asm[(wr * 64 + t * 16 + (lane & 15)) * 40 + (lane >> 4) * 8];
            bfr[t] = *(const s16x8*)&Bsm[(wc * 64 + t * 16 + (lane & 15)) * 40 + (lane >> 4) * 8];
        }
#pragma unroll
        for (int mf = 0; mf < 4; ++mf)
#pragma unroll
            for (int nf = 0; nf < 4; ++nf)
                acc[mf][nf] = __builtin_amdgcn_mfma_f32_16x16x32_bf16(
                    af[mf], bfr[nf], acc[mf][nf], 0, 0, 0);
        __syncthreads();
    }

#pragma unroll
    for (int mf = 0; mf < 4; ++mf)
#pragma unroll
        for (int nf = 0; nf < 4; ++nf) {
            const int col = bn + wc * 64 + nf * 16 + (lane & 15);
            const float bv_ = bias ? bias[col] : 0.f;
#pragma unroll
            for (int i = 0; i < 4; ++i) {
                const int row = bm + wr * 64 + mf * 16 + (lane >> 4) * 4 + i;
                const float v = acc[mf][nf][i] + bv_;
                if (SM == 1)
                    stf(&Cout[((size_t)(row >> 8) * N + col) * 256 + (row & 255)], v);
                else
                    stf(&Cout[(size_t)row * N + col], v);
            }
        }
}

// ---------------------------------------------------------------------------
// GRU scan v10: v9's 12-wave structure + h-through-registers.
// r12 closure: v9 is LDS-throughput-bound (192 b128 slots/CU-step x ~12cyc
// = measured 2490 cyc). 96 weight slots are optimal (1KB each); the 96
// h-BROADCAST slots deliver 16B each -- pure waste. v10: ONE lane-spread
// h-b128 per thread (lane&7 owns a 16B chunk, 8-way replicated) + 32
// readlane (VALU pipe, literal lane) to redistribute. LDS 16->9 slots per
// thread-step. v8 already proved readlane-h correct; its regression was
// 1.5 waves/SIMD occupancy, fixed here by the 768-thread k-split layout.
// ---------------------------------------------------------------------------
__global__ __launch_bounds__(768, 1)
void gru_scan_v10(const bf16* __restrict__ gx, const float* __restrict__ w_hh,
                  const float* __restrict__ b_hh, bf16* __restrict__ out)
{
    const int b = blockIdx.x, dir = blockIdx.y;
    const int t = threadIdx.x;
    const int half = t >= 384 ? 1 : 0;
    const int r = t - 384 * half;            // gate row 0..383
    const int lane = t & 63;
    __shared__ __align__(16) ushort wl[384 * 136];   // 272B rows, 104448 B
    __shared__ __align__(16) ushort hp16[128];       // h as f16 (256 B)
    __shared__ float h_sh[128];
    __shared__ float part[384];
    __shared__ float rs[128], zs[128], gxn[128], ghn[128];

    // stage weights once (coalesced 8B loads)
    const float* wbase = w_hh + (size_t)dir * G3n * Hn;
    for (int idx = t; idx < G3n * 64; idx += 768) {
        const int row = idx >> 6, k2 = idx & 63;
        const float2 v = *(const float2*)(wbase + row * Hn + 2 * k2);
        h16x2 p; p[0] = (_Float16)v.x; p[1] = (_Float16)v.y;
        *(h16x2*)&wl[row * 136 + 2 * k2] = p;
    }
    if (t < 128) { hp16[t] = 0; h_sh[t] = 0.f; }
    const float bh = b_hh[dir * G3n + r];
    __syncthreads();

    const size_t g0 = (size_t)b * Ln * 768 + dir * G3n + r
                      + (dir ? (size_t)(Ln - 1) * 768 : 0);
    const long gstep = dir ? -768L : 768L;
    float gcur = 0.f, gnx = 0.f;
    if (!half) { gcur = ldf(&gx[g0]); gnx = ldf(&gx[g0 + gstep]); }

    const ushort* wrow = &wl[r * 136 + half * 64];   // this half's 64 weights

    for (int s = 0; s < Ln; ++s) {
        const int tt = dir ? (Ln - 1 - s) : s;
        float gn2 = 0.f;
        if (!half && s + 2 < Ln) gn2 = ldf(&gx[g0 + (long)(s + 2) * gstep]);

        // lane's own h chunk: 16B; 8 distinct addrs/wave (8-way bcast merge)
        const float4 hown = *(const float4*)&hp16[half * 64 + (lane & 7) * 8];

        float a0 = 0.f, a1 = 0.f, a2 = 0.f, a3 = 0.f;
#pragma unroll
        for (int j = 0; j < 8; ++j) {
            const float4 wv = *(const float4*)&wrow[8 * j];  // k [8j, 8j+8)
            a0 = dot2f(BCH(wv.x), BCH(rdl(hown.x, j)), a0);
            a1 = dot2f(BCH(wv.y), BCH(rdl(hown.y, j)), a1);
            a2 = dot2f(BCH(wv.z), BCH(rdl(hown.z, j)), a2);
            a3 = dot2f(BCH(wv.w), BCH(rdl(hown.w, j)), a3);
        }
        const float acc = (a0 + a1) + (a2 + a3);
        if (half) part[r] = acc;
        __syncthreads();

        if (!half) {
            const float tot = acc + part[r] + bh;
            if (r < 128)      rs[r]       = 1.f / (1.f + expf(-(gcur + tot)));
            else if (r < 256) zs[r - 128] = 1.f / (1.f + expf(-(gcur + tot)));
            else { gxn[r - 256] = gcur; ghn[r - 256] = tot; }
        }
        __syncthreads();

        if (t < 128) {
            const int j = t;
            const float nn = tanhf(gxn[j] + rs[j] * ghn[j]);
            const float hnew = (1.f - zs[j]) * nn + zs[j] * h_sh[j];
            h_sh[j] = hnew;
            const _Float16 hf = (_Float16)hnew;
            hp16[j] = __builtin_bit_cast(ushort, hf);
            out[((size_t)b * Ln + tt) * Dn + dir * Hn + j] = __float2bfloat16(hnew);
        }
        __syncthreads();
        if (!half) { gcur = gnx; gnx = gn2; }
    }
}

// ---------------------------------------------------------------------------
// attn score, MFMA, fused channels: grid (2, B, C); mat row stride 1024.
// ---------------------------------------------------------------------------
__global__ __launch_bounds__(256)
void attn_score_mfma(const bf16* __restrict__ x, const bf16* __restrict__ matb,
                     const float* __restrict__ attb, float* __restrict__ sout)
{
    const int it = blockIdx.x, b = blockIdx.y, c = blockIdx.z;
    const bf16* A  = x + ((size_t)b * 256 + it * 128) * 256;
    const bf16* Bm = matb + (size_t)b * 256 * 1024 + c * 256;
    __shared__ ushort Xs[128 * 40];
    __shared__ ushort Ms[128 * 40];
    const int tid = threadIdx.x, lane = tid & 63, w = tid >> 6;
    const float bc = attb[c];
    float psum[2][4] = {};

    for (int jt = 0; jt < 2; ++jt) {
        f32x4 acc[2][8] = {};
        for (int kt = 0; kt < 8; ++kt) {
            const int k0 = kt << 5;
#pragma unroll
            for (int u = 0; u < 2; ++u) {
                const int idx = tid + u * 256;
                const int m = idx >> 2, q = idx & 3;
                *(s16x8*)&Xs[m * 40 + q * 8] =
                    *(const s16x8*)&A[(size_t)m * 256 + k0 + q * 8];
                *(s16x8*)&Ms[m * 40 + q * 8] =
                    *(const s16x8*)&Bm[(size_t)(jt * 128 + m) * 1024 + k0 + q * 8];
            }
            __syncthreads();
            s16x8 af[2], bfr[8];
#pragma unroll
            for (int t = 0; t < 2; ++t)
                af[t] = *(const s16x8*)&Xs[(w * 32 + t * 16 + (lane & 15)) * 40 + (lane >> 4) * 8];
#pragma unroll
            for (int t = 0; t < 8; ++t)
                bfr[t] = *(const s16x8*)&Ms[(t * 16 + (lane & 15)) * 40 + (lane >> 4) * 8];
#pragma unroll
            for (int mf = 0; mf < 2; ++mf)
#pragma unroll
                for (int nf = 0; nf < 8; ++nf)
                    acc[mf][nf] = __builtin_amdgcn_mfma_f32_16x16x32_bf16(
                        af[mf], bfr[nf], acc[mf][nf], 0, 0, 0);
            __syncthreads();
        }
#pragma unroll
        for (int mf = 0; mf < 2; ++mf)
#pragma unroll
            for (int nf = 0; nf < 8; ++nf)
#pragma unroll
                for (int i = 0; i < 4; ++i)
                    psum[mf][i] += tanhf(acc[mf][nf][i] + bc);
    }

#pragma unroll
    for (int mf = 0; mf < 2; ++mf)
#pragma unroll
        for (int i = 0; i < 4; ++i) {
            float v = psum[mf][i];
            v += __shfl_xor(v, 1); v += __shfl_xor(v, 2);
            v += __shfl_xor(v, 4); v += __shfl_xor(v, 8);
            if ((lane & 15) == 0)
                sout[(size_t)c * BLn + b * 256 + it * 128 + w * 32 + mf * 16 + (lane >> 4) * 4 + i] = v;
        }
}

// al[c,row] = sum_e sigmoid(gv[row, c*256+e] + bv[c,e]) * wv1[c,e]
__global__ __launch_bounds__(256)
void gv_reduce(const bf16* __restrict__ gv, const float* __restrict__ bv,
               const float* __restrict__ wv1, float* __restrict__ al)
{
    const int row = blockIdx.x * 4 + (threadIdx.x >> 6);
    const int c = blockIdx.y;
    const int l = threadIdx.x & 63;
    const ushort4 u = *(const ushort4*)&gv[(size_t)row * 1024 + c * 256 + l * 4];
    const float4 bb = *(const float4*)(bv + c * Dn + l * 4);
    const float4 w  = *(const float4*)(wv1 + c * Dn + l * 4);
    float s = w.x / (1.f + expf(-(bfu(u.x) + bb.x)))
            + w.y / (1.f + expf(-(bfu(u.y) + bb.y)))
            + w.z / (1.f + expf(-(bfu(u.z) + bb.z)))
            + w.w / (1.f + expf(-(bfu(u.w) + bb.w)));
#pragma unroll
    for (int m = 1; m < 64; m <<= 1) s += __shfl_xor(s, m);
    if (l == 0) al[(size_t)c * BLn + row] = s;
}

// transpose 4 matrices of 256x256 (src[c][d][e] fp32 -> dst[c][e][d] bf16)
__global__ void transpose256(const float* __restrict__ src, bf16* __restrict__ dst)
{
    const float* s = src + (size_t)blockIdx.x * 65536;
    bf16* d = dst + (size_t)blockIdx.x * 65536;
    __shared__ float t[32][33];
    const int tx = threadIdx.x & 31, ty8 = threadIdx.x >> 5;
    for (int bi = 0; bi < 8; ++bi)
        for (int bj = 0; bj < 8; ++bj) {
            __syncthreads();
            for (int r = ty8; r < 32; r += 8)
                t[r][tx] = s[(size_t)(bi * 32 + r) * 256 + bj * 32 + tx];
            __syncthreads();
            for (int r = ty8; r < 32; r += 8)
                stf(&d[(size_t)(bj * 32 + r) * 256 + bi * 32 + tx], t[tx][r]);
        }
}

__global__ void softmax256(const float* __restrict__ in, float* __restrict__ out)
{
    __shared__ float red[256];
    const int row = blockIdx.x, t = threadIdx.x;
    const float v = in[(size_t)row * 256 + t];
    red[t] = v; __syncthreads();
    for (int off = 128; off; off >>= 1) {
        if (t < off) red[t] = fmaxf(red[t], red[t + off]);
        __syncthreads();
    }
    const float mx = red[0]; __syncthreads();
    const float e = expf(v - mx);
    red[t] = e; __syncthreads();
    for (int off = 128; off; off >>= 1) {
        if (t < off) red[t] += red[t + off];
        __syncthreads();
    }
    out[(size_t)row * 256 + t] = e / red[0];
}

// new[c,b,d] for all 4 c in one pass over x (x read once per b)
__global__ __launch_bounds__(256)
void weighted_sum_kernel(const float* __restrict__ aa,
                         const bf16* __restrict__ x,
                         float* __restrict__ outnew)
{
    const int b = blockIdx.x, d = threadIdx.x;
    __shared__ float w4[4][Ln];
    for (int i = d; i < 4 * Ln; i += 256)
        w4[i >> 8][i & 255] = aa[((size_t)(i >> 8) * Bn + b) * Ln + (i & 255)];
    __syncthreads();
    float a0 = 0.f, a1 = 0.f, a2 = 0.f, a3 = 0.f;
    for (int l = 0; l < Ln; ++l) {
        const float xv = ldf(&x[((size_t)b * Ln + l) * Dn + d]);
        a0 += w4[0][l] * xv; a1 += w4[1][l] * xv;
        a2 += w4[2][l] * xv; a3 += w4[3][l] * xv;
    }
    outnew[((size_t)0 * Bn + b) * Dn + d] = a0;
    outnew[((size_t)1 * Bn + b) * Dn + d] = a1;
    outnew[((size_t)2 * Bn + b) * Dn + d] = a2;
    outnew[((size_t)3 * Bn + b) * Dn + d] = a3;
}

// pack conv filter rows (216) into 256x256 fp32 (rows 216+ zero)
__global__ void wpack_fill(const float* __restrict__ w0, const float* __restrict__ w1,
                           const float* __restrict__ w2, const float* __restrict__ w3,
                           float* __restrict__ wp)
{
    const int f = blockIdx.x;
    if (f < 4) {
        const int cnt[4]  = {4096, 9216, 16384, 25600};
        const int boff[4] = {0, 4096, 13312, 29696};
        const float* src = f == 0 ? w0 : f == 1 ? w1 : f == 2 ? w2 : w3;
        for (int i = threadIdx.x; i < cnt[f]; i += blockDim.x)
            wp[boff[f] + i] = src[i];
    } else {
        for (int i = threadIdx.x; i < 65536 - 55296; i += blockDim.x)
            wp[55296 + i] = 0.f;
    }
}

// nwd[b,row] = dot(new[c_of_row, b, :], wpack[row, :])
__global__ __launch_bounds__(256)
void nwd_kernel(const float* __restrict__ nw, const float* __restrict__ wp,
                float* __restrict__ nwd)
{
    const int b = blockIdx.x;
    __shared__ float ns[4][256];
    for (int i = threadIdx.x; i < 1024; i += 256)
        ns[i >> 8][i & 255] = nw[((size_t)((i >> 8) * Bn + b) << 8) + (i & 255)];
    __syncthreads();
    const int row = threadIdx.x;
    if (row < 216) {
        int f, base;
        if (row < 16)       { f = 0; base = 0; }
        else if (row < 52)  { f = 1; base = 16; }
        else if (row < 116) { f = 2; base = 52; }
        else                { f = 3; base = 116; }
        const int fs = f + 2, local = row - base;
        const int c = (local / fs) & 3;
        const float* wr = wp + (size_t)row * 256;
        float acc = 0.f;
        for (int k = 0; k < 256; ++k) acc += ns[c][k] * wr[k];
        nwd[b * 256 + row] = acc;
    }
}

// conv+relu+maxpool via decomposition over a-weighted x rows + new offset
__global__ __launch_bounds__(256)
void conv_combine(const float* __restrict__ xwT, const float* __restrict__ a,
                  const float* __restrict__ nwd, const float* __restrict__ cb,
                  float* __restrict__ pool, int fs, int base, int poff)
{
    const int b = blockIdx.x, tid = threadIdx.x;
    __shared__ float ash[4][256];
    __shared__ float basev[5];
    __shared__ float red[256];
    for (int i = tid; i < 1024; i += 256)
        ash[i >> 8][i & 255] = a[((size_t)((i >> 8) * Bn + b) << 8) + (i & 255)];
    if (tid < fs) {
        float s = cb[tid];
        for (int c = 0; c < 4; ++c)
            for (int kh = 0; kh < fs; ++kh)
                s += nwd[b * 256 + base + (tid * 4 + c) * fs + kh];
        basev[tid] = s;
    }
    __syncthreads();
    const int ni = Ln - fs + 1;
    const float* xb = xwT + ((size_t)b << 16);
    for (int o = 0; o < fs; ++o) {
        float best = 0.f;
        if (tid < ni) {
            float acc = basev[o];
            for (int c = 0; c < 4; ++c)
                for (int kh = 0; kh < fs; ++kh) {
                    const int row = base + (o * 4 + c) * fs + kh;
                    acc += ash[c][tid + kh] * xb[(row << 8) + tid + kh];
                }
            best = fmaxf(acc, 0.f);
        }
        red[tid] = best; __syncthreads();
        for (int off = 128; off; off >>= 1) {
            if (tid < off) red[tid] = fmaxf(red[tid], red[tid + off]);
            __syncthreads();
        }
        if (tid == 0) pool[b * 14 + poff + o] = red[0];
        __syncthreads();
    }
}

__global__ void fc_kernel(const float* __restrict__ pool, const float* __restrict__ fw,
                          const float* __restrict__ fb, float* __restrict__ out)
{
    const int i = threadIdx.x;           // 256 = B*OUT
    const int b = i >> 1, o = i & 1;
    float acc = fb[o];
#pragma unroll
    for (int f = 0; f < 14; ++f) acc += pool[b * 14 + f] * fw[o * 14 + f];
    out[i] = acc;
}

// ---------------------------------------------------------------------------
extern "C" void kernel_launch(void* const* d_in, const int* in_sizes, int n_in,
                              void* d_out, int out_size, void* d_ws, size_t ws_size,
                              hipStream_t stream)
{
    const int*   utt    = (const int*)  d_in[0];
    const float* emb    = (const float*)d_in[2];
    const float* w_ih0  = (const float*)d_in[3];
    const float* w_hh0  = (const float*)d_in[4];
    const float* b_ih0  = (const float*)d_in[5];
    const float* b_hh0  = (const float*)d_in[6];
    const float* w_ih1  = (const float*)d_in[7];
    const float* w_hh1  = (const float*)d_in[8];
    const float* b_ih1  = (const float*)d_in[9];
    const float* b_hh1  = (const float*)d_in[10];
    const float* att_w  = (const float*)d_in[11];
    const float* att_b  = (const float*)d_in[12];
    const float* att_wv2= (const float*)d_in[13];
    const float* att_bv = (const float*)d_in[14];
    const float* att_wv1= (const float*)d_in[15];
    const float* fc_w   = (const float*)d_in[16];
    const float* fc_b   = (const float*)d_in[17];
    const float* cw[4] = {(const float*)d_in[18], (const float*)d_in[20],
                          (const float*)d_in[22], (const float*)d_in[24]};
    const float* cb[4] = {(const float*)d_in[19], (const float*)d_in[21],
                          (const float*)d_in[23], (const float*)d_in[25]};

    float* ws = (float*)d_ws;
    bf16*  GX   = (bf16*)ws;                          // [0, 12.58M f32)
    bf16*  H1   = (bf16*)(ws + 12582912);             // [12.58M, 16.78M)
    bf16*  H2   = (bf16*)(ws + 16777216);             // [16.78M, 20.97M)
    bf16*  WT   = (bf16*)(ws + 20971520);             //   131,072 f32 slots
    float* WP   = ws + 20971520 + 131072;             //    65,536 f
    float* S    = WP + 65536;                         //   131,072 f
    float* Aa   = S + 131072;
    float* AL   = Aa + 131072;
    float* AAa  = AL + 131072;
    float* NEW_ = AAa + 131072;
    float* NWD  = NEW_ + 131072;                      //    32,768 f
    float* POOL = NWD + 32768;                        //     1,792 f
    bf16*  MATB = (bf16*)ws;   // fused-channel MAT/GV, 67MB over dead GX+H1
    float* XWT  = ws;

    // layer 0 + scan
    gemm_mfma<float, float, bf16, true, 0><<<dim3(6, 256), 256, 0, stream>>>(
        emb, w_ih0, b_ih0, GX, utt, BLn, 768, En);
    gru_scan_v10<<<dim3(Bn, 2), 768, 0, stream>>>(GX, w_hh0, b_hh0, H1);
    // layer 1 + scan
    gemm_mfma<bf16, float, bf16, false, 0><<<dim3(6, 256), 256, 0, stream>>>(
        H1, w_ih1, b_ih1, GX, nullptr, BLn, 768, Dn);
    gru_scan_v10<<<dim3(Bn, 2), 768, 0, stream>>>(GX, w_hh1, b_hh1, H2);

    // scalar attention: MATB = x @ [att_w^T stacked], fused 4-channel scores
    transpose256<<<4, 256, 0, stream>>>(att_w, WT);
    gemm_mfma<bf16, bf16, bf16, false, 0><<<dim3(8, 256), 256, 0, stream>>>(
        H2, WT, nullptr, MATB, nullptr, BLn, 1024, Dn);
    attn_score_mfma<<<dim3(2, Bn, Cn), 256, 0, stream>>>(H2, MATB, att_b, S);
    softmax256<<<Cn * Bn, 256, 0, stream>>>(S, Aa);

    // vector attention: GVB = x @ [wv2^T stacked], fused reduce
    transpose256<<<4, 256, 0, stream>>>(att_wv2, WT);
    gemm_mfma<bf16, bf16, bf16, false, 0><<<dim3(8, 256), 256, 0, stream>>>(
        H2, WT, nullptr, MATB, nullptr, BLn, 1024, Dn);
    gv_reduce<<<dim3(BLn / 4, Cn), 256, 0, stream>>>(MATB, att_bv, att_wv1, AL);
    softmax256<<<Cn * Bn, 256, 0, stream>>>(AL, AAa);
    weighted_sum_kernel<<<Bn, 256, 0, stream>>>(AAa, H2, NEW_);

    // conv stage via xw GEMM decomposition (Cf never materialized)
    wpack_fill<<<5, 256, 0, stream>>>(cw[0], cw[1], cw[2], cw[3], WP);
    gemm_mfma<bf16, float, float, false, 1><<<dim3(2, 256), 256, 0, stream>>>(
        H2, WP, nullptr, XWT, nullptr, BLn, Dn, Dn);
    nwd_kernel<<<Bn, 256, 0, stream>>>(NEW_, WP, NWD);

    const int baserow[4] = {0, 16, 52, 116};
    const int poff[4]    = {0, 2, 5, 9};
    for (int f = 0; f < 4; ++f)
        conv_combine<<<Bn, 256, 0, stream>>>(XWT, Aa, NWD, cb[f], POOL, f + 2, baserow[f], poff[f]);

    fc_kernel<<<1, 256, 0, stream>>>(POOL, fc_w, fc_b, (float*)d_out);
}

// Round 14
// 1095.821 us; speedup vs baseline: 1.0722x; 1.0722x over previous
//
#include <hip/hip_runtime.h>
#include <hip/hip_bf16.h>
#include <hip/hip_fp16.h>

#define Bn  128
#define Ln  256
#define En  300
#define Hn  128
#define Cn  4
#define Dn  256     // 2H
#define G3n 384     // 3H
#define BLn (Bn * Ln)   // 32768

typedef __hip_bfloat16 bf16;
typedef short s16x8 __attribute__((ext_vector_type(8)));
typedef float f32x4 __attribute__((ext_vector_type(4)));
typedef _Float16 h16x2 __attribute__((ext_vector_type(2)));

__device__ __forceinline__ float ldf(const float* p) { return *p; }
__device__ __forceinline__ float ldf(const bf16* p)  { return __bfloat162float(*p); }
__device__ __forceinline__ void stf(float* p, float v) { *p = v; }
__device__ __forceinline__ void stf(bf16* p, float v)  { *p = __float2bfloat16(v); }

__device__ __forceinline__ ushort f2bf(float f) {
    bf16 h = __float2bfloat16(f);
    return *reinterpret_cast<ushort*>(&h);
}
__device__ __forceinline__ float bfu(ushort x) {
    unsigned t = ((unsigned)x) << 16;
    return __builtin_bit_cast(float, t);
}

#if __has_builtin(__builtin_amdgcn_fdot2)
__device__ __forceinline__ float dot2f(h16x2 w, h16x2 h, float c) {
    return __builtin_amdgcn_fdot2(w, h, c, false);
}
#else
__device__ __forceinline__ float dot2f(h16x2 w, h16x2 h, float c) {
    return fmaf((float)w[0], (float)h[0], fmaf((float)w[1], (float)h[1], c));
}
#endif
#define BCH(x) __builtin_bit_cast(h16x2, x)

// 16B-or-8B load of 4 values, fp32 or bf16 source
__device__ __forceinline__ float4 ld4f(const float* p) { return *(const float4*)p; }
__device__ __forceinline__ float4 ld4f(const bf16* p) {
    ushort4 u = *(const ushort4*)p;
    return make_float4(bfu(u.x), bfu(u.y), bfu(u.z), bfu(u.w));
}

// ---------------------------------------------------------------------------
// MFMA bf16 GEMM: C[M,N] = A[M,K] * W^T + bias   (W is (N,K) row-major)
//   AT/WTp in {float,bf16}; GATHER: A row m = A[gidx[m]*K ..]
//   SM==1: store C[(m>>8),n,(m&255)]
// ---------------------------------------------------------------------------
template<class AT, class WTp, class OT, bool GATHER, int SM>
__global__ __launch_bounds__(256)
void gemm_mfma(const AT* __restrict__ A, const WTp* __restrict__ W,
               const float* __restrict__ bias, OT* __restrict__ Cout,
               const int* __restrict__ gidx, int M, int N, int K)
{
    __shared__ ushort Asm[128 * 40];
    __shared__ ushort Bsm[128 * 40];
    const int bm = blockIdx.y * 128, bn = blockIdx.x * 128;
    const int tid = threadIdx.x;
    const int lane = tid & 63, w = tid >> 6, wr = w >> 1, wc = w & 1;

    const AT* arow[4];
    const WTp* brow[4];
#pragma unroll
    for (int u = 0; u < 4; ++u) {
        const int idx = tid + u * 256;
        const int m = idx >> 3;
        arow[u] = A + (size_t)(GATHER ? gidx[bm + m] : (bm + m)) * K;
        brow[u] = W + (size_t)(bn + m) * K;
    }

    f32x4 acc[4][4] = {};
    const int nkt = (K + 31) >> 5;
    for (int kt = 0; kt < nkt; ++kt) {
        const int k0 = kt << 5;
#pragma unroll
        for (int u = 0; u < 4; ++u) {
            const int idx = tid + u * 256;
            const int m = idx >> 3, kq = idx & 7;
            const int kb = k0 + kq * 4;
            float4 v, q;
            if (kb + 4 <= K) {
                v = ld4f(arow[u] + kb);
                q = ld4f(brow[u] + kb);
            } else {
                v.x = kb + 0 < K ? ldf(&arow[u][kb + 0]) : 0.f;
                v.y = kb + 1 < K ? ldf(&arow[u][kb + 1]) : 0.f;
                v.z = kb + 2 < K ? ldf(&arow[u][kb + 2]) : 0.f;
                v.w = kb + 3 < K ? ldf(&arow[u][kb + 3]) : 0.f;
                q.x = kb + 0 < K ? ldf(&brow[u][kb + 0]) : 0.f;
                q.y = kb + 1 < K ? ldf(&brow[u][kb + 1]) : 0.f;
                q.z = kb + 2 < K ? ldf(&brow[u][kb + 2]) : 0.f;
                q.w = kb + 3 < K ? ldf(&brow[u][kb + 3]) : 0.f;
            }
            *(ushort4*)&Asm[m * 40 + kq * 4] =
                make_ushort4(f2bf(v.x), f2bf(v.y), f2bf(v.z), f2bf(v.w));
            *(ushort4*)&Bsm[m * 40 + kq * 4] =
                make_ushort4(f2bf(q.x), f2bf(q.y), f2bf(q.z), f2bf(q.w));
        }
        __syncthreads();
        s16x8 af[4], bfr[4];
#pragma unroll
        for (int t = 0; t < 4; ++t) {
            af[t]  = *(const s16x8*)&Asm[(wr * 64 + t * 16 + (lane & 15)) * 40 + (lane >> 4) * 8];
            bfr[t] = *(const s16x8*)&Bsm[(wc * 64 + t * 16 + (lane & 15)) * 40 + (lane >> 4) * 8];
        }
#pragma unroll
        for (int mf = 0; mf < 4; ++mf)
#pragma unroll
            for (int nf = 0; nf < 4; ++nf)
                acc[mf][nf] = __builtin_amdgcn_mfma_f32_16x16x32_bf16(
                    af[mf], bfr[nf], acc[mf][nf], 0, 0, 0);
        __syncthreads();
    }

#pragma unroll
    for (int mf = 0; mf < 4; ++mf)
#pragma unroll
        for (int nf = 0; nf < 4; ++nf) {
            const int col = bn + wc * 64 + nf * 16 + (lane & 15);
            const float bv_ = bias ? bias[col] : 0.f;
#pragma unroll
            for (int i = 0; i < 4; ++i) {
                const int row = bm + wr * 64 + mf * 16 + (lane >> 4) * 4 + i;
                const float v = acc[mf][nf][i] + bv_;
                if (SM == 1)
                    stf(&Cout[((size_t)(row >> 8) * N + col) * 256 + (row & 255)], v);
                else
                    stf(&Cout[(size_t)row * N + col], v);
            }
        }
}

// ---------------------------------------------------------------------------
// gv GEMM + fused sigmoid-weighted row reduction (replaces 67MB gv write +
// 67MB read + 32768-block gv_reduce). A: x bf16 (M=BLn,K=256); W: wv2^T
// stacked bf16 (N=1024 rows of K=256). Epilogue: al[c,m] += sum_col
// sigmoid(acc + bv[col]) * wv1[col], via 16-lane shfl reduce + atomicAdd.
// Block cols (128) lie within one channel c = bn>>8 (128 | 256). AL must be
// zeroed before launch (hipMemsetAsync).
// ---------------------------------------------------------------------------
__global__ __launch_bounds__(256)
void gv_gemm_reduce(const bf16* __restrict__ A, const bf16* __restrict__ W,
                    const float* __restrict__ bv, const float* __restrict__ wv1,
                    float* __restrict__ al)
{
    __shared__ ushort Asm[128 * 40];
    __shared__ ushort Bsm[128 * 40];
    const int bm = blockIdx.y * 128, bn = blockIdx.x * 128;
    const int tid = threadIdx.x;
    const int lane = tid & 63, w = tid >> 6, wr = w >> 1, wc = w & 1;

    f32x4 acc[4][4] = {};
    for (int kt = 0; kt < 8; ++kt) {
        const int k0 = kt << 5;
#pragma unroll
        for (int u = 0; u < 2; ++u) {        // straight 16B copies (bf16 src)
            const int idx = tid + u * 256;
            const int m = idx >> 2, q = idx & 3;
            *(s16x8*)&Asm[m * 40 + q * 8] =
                *(const s16x8*)&A[(size_t)(bm + m) * 256 + k0 + q * 8];
            *(s16x8*)&Bsm[m * 40 + q * 8] =
                *(const s16x8*)&W[(size_t)(bn + m) * 256 + k0 + q * 8];
        }
        __syncthreads();
        s16x8 af[4], bfr[4];
#pragma unroll
        for (int t = 0; t < 4; ++t) {
            af[t]  = *(const s16x8*)&Asm[(wr * 64 + t * 16 + (lane & 15)) * 40 + (lane >> 4) * 8];
            bfr[t] = *(const s16x8*)&Bsm[(wc * 64 + t * 16 + (lane & 15)) * 40 + (lane >> 4) * 8];
        }
#pragma unroll
        for (int mf = 0; mf < 4; ++mf)
#pragma unroll
            for (int nf = 0; nf < 4; ++nf)
                acc[mf][nf] = __builtin_amdgcn_mfma_f32_16x16x32_bf16(
                    af[mf], bfr[nf], acc[mf][nf], 0, 0, 0);
        __syncthreads();
    }

    float bb[4], wv[4];
#pragma unroll
    for (int nf = 0; nf < 4; ++nf) {
        const int col = bn + wc * 64 + nf * 16 + (lane & 15);
        bb[nf] = bv[col];
        wv[nf] = wv1[col];
    }
    const size_t cbase = (size_t)(bn >> 8) * BLn;
#pragma unroll
    for (int mf = 0; mf < 4; ++mf)
#pragma unroll
        for (int i = 0; i < 4; ++i) {
            float p = 0.f;
#pragma unroll
            for (int nf = 0; nf < 4; ++nf)
                p += wv[nf] / (1.f + expf(-(acc[mf][nf][i] + bb[nf])));
            p += __shfl_xor(p, 1); p += __shfl_xor(p, 2);
            p += __shfl_xor(p, 4); p += __shfl_xor(p, 8);
            if ((lane & 15) == 0) {
                const int row = bm + wr * 64 + mf * 16 + (lane >> 4) * 4 + i;
                atomicAdd(&al[cbase + row], p);
            }
        }
}

// ---------------------------------------------------------------------------
// GRU scan v9 (round-12 best: 266us). k-split over 768 threads (12 waves).
// LDS-throughput bound: 192 b128 slots/CU-step. v10's readlane variant
// regressed (serial dep on one ds_read); v9 is the settled floor.
// ---------------------------------------------------------------------------
__global__ __launch_bounds__(768, 1)
void gru_scan_v9(const bf16* __restrict__ gx, const float* __restrict__ w_hh,
                 const float* __restrict__ b_hh, bf16* __restrict__ out)
{
    const int b = blockIdx.x, dir = blockIdx.y;
    const int t = threadIdx.x;
    const int half = t >= 384 ? 1 : 0;
    const int r = t - 384 * half;            // gate row 0..383
    __shared__ __align__(16) ushort wl[384 * 136];   // 272B rows, 104448 B
    __shared__ __align__(16) ushort hp16[128];       // h as f16
    __shared__ float h_sh[128];
    __shared__ float part[384];
    __shared__ float rs[128], zs[128], gxn[128], ghn[128];

    const float* wbase = w_hh + (size_t)dir * G3n * Hn;
    for (int idx = t; idx < G3n * 64; idx += 768) {
        const int row = idx >> 6, k2 = idx & 63;
        const float2 v = *(const float2*)(wbase + row * Hn + 2 * k2);
        h16x2 p; p[0] = (_Float16)v.x; p[1] = (_Float16)v.y;
        *(h16x2*)&wl[row * 136 + 2 * k2] = p;
    }
    if (t < 128) { hp16[t] = 0; h_sh[t] = 0.f; }
    const float bh = b_hh[dir * G3n + r];
    __syncthreads();

    const size_t g0 = (size_t)b * Ln * 768 + dir * G3n + r
                      + (dir ? (size_t)(Ln - 1) * 768 : 0);
    const long gstep = dir ? -768L : 768L;
    float gcur = 0.f, gnx = 0.f;
    if (!half) { gcur = ldf(&gx[g0]); gnx = ldf(&gx[g0 + gstep]); }

    const ushort* wrow  = &wl[r * 136 + half * 64];
    const ushort* hbase = &hp16[half * 64];

    for (int s = 0; s < Ln; ++s) {
        const int tt = dir ? (Ln - 1 - s) : s;
        float gn2 = 0.f;
        if (!half && s + 2 < Ln) gn2 = ldf(&gx[g0 + (long)(s + 2) * gstep]);

        float a0 = 0.f, a1 = 0.f, a2 = 0.f, a3 = 0.f;
#pragma unroll
        for (int j = 0; j < 8; ++j) {
            const float4 wv = *(const float4*)&wrow[8 * j];
            const float4 hv = *(const float4*)&hbase[8 * j];
            a0 = dot2f(BCH(wv.x), BCH(hv.x), a0);
            a1 = dot2f(BCH(wv.y), BCH(hv.y), a1);
            a2 = dot2f(BCH(wv.z), BCH(hv.z), a2);
            a3 = dot2f(BCH(wv.w), BCH(hv.w), a3);
        }
        const float acc = (a0 + a1) + (a2 + a3);
        if (half) part[r] = acc;
        __syncthreads();

        if (!half) {
            const float tot = acc + part[r] + bh;
            if (r < 128)      rs[r]       = 1.f / (1.f + expf(-(gcur + tot)));
            else if (r < 256) zs[r - 128] = 1.f / (1.f + expf(-(gcur + tot)));
            else { gxn[r - 256] = gcur; ghn[r - 256] = tot; }
        }
        __syncthreads();

        if (t < 128) {
            const int j = t;
            const float nn = tanhf(gxn[j] + rs[j] * ghn[j]);
            const float hnew = (1.f - zs[j]) * nn + zs[j] * h_sh[j];
            h_sh[j] = hnew;
            const _Float16 hf = (_Float16)hnew;
            hp16[j] = __builtin_bit_cast(ushort, hf);
            out[((size_t)b * Ln + tt) * Dn + dir * Hn + j] = __float2bfloat16(hnew);
        }
        __syncthreads();
        if (!half) { gcur = gnx; gnx = gn2; }
    }
}

// ---------------------------------------------------------------------------
// attn score, MFMA, fused channels: grid (2, B, C); mat row stride 1024.
// ---------------------------------------------------------------------------
__global__ __launch_bounds__(256)
void attn_score_mfma(const bf16* __restrict__ x, const bf16* __restrict__ matb,
                     const float* __restrict__ attb, float* __restrict__ sout)
{
    const int it = blockIdx.x, b = blockIdx.y, c = blockIdx.z;
    const bf16* A  = x + ((size_t)b * 256 + it * 128) * 256;
    const bf16* Bm = matb + (size_t)b * 256 * 1024 + c * 256;
    __shared__ ushort Xs[128 * 40];
    __shared__ ushort Ms[128 * 40];
    const int tid = threadIdx.x, lane = tid & 63, w = tid >> 6;
    const float bc = attb[c];
    float psum[2][4] = {};

    for (int jt = 0; jt < 2; ++jt) {
        f32x4 acc[2][8] = {};
        for (int kt = 0; kt < 8; ++kt) {
            const int k0 = kt << 5;
#pragma unroll
            for (int u = 0; u < 2; ++u) {
                const int idx = tid + u * 256;
                const int m = idx >> 2, q = idx & 3;
                *(s16x8*)&Xs[m * 40 + q * 8] =
                    *(const s16x8*)&A[(size_t)m * 256 + k0 + q * 8];
                *(s16x8*)&Ms[m * 40 + q * 8] =
                    *(const s16x8*)&Bm[(size_t)(jt * 128 + m) * 1024 + k0 + q * 8];
            }
            __syncthreads();
            s16x8 af[2], bfr[8];
#pragma unroll
            for (int t = 0; t < 2; ++t)
                af[t] = *(const s16x8*)&Xs[(w * 32 + t * 16 + (lane & 15)) * 40 + (lane >> 4) * 8];
#pragma unroll
            for (int t = 0; t < 8; ++t)
                bfr[t] = *(const s16x8*)&Ms[(t * 16 + (lane & 15)) * 40 + (lane >> 4) * 8];
#pragma unroll
            for (int mf = 0; mf < 2; ++mf)
#pragma unroll
                for (int nf = 0; nf < 8; ++nf)
                    acc[mf][nf] = __builtin_amdgcn_mfma_f32_16x16x32_bf16(
                        af[mf], bfr[nf], acc[mf][nf], 0, 0, 0);
            __syncthreads();
        }
#pragma unroll
        for (int mf = 0; mf < 2; ++mf)
#pragma unroll
            for (int nf = 0; nf < 8; ++nf)
#pragma unroll
                for (int i = 0; i < 4; ++i)
                    psum[mf][i] += tanhf(acc[mf][nf][i] + bc);
    }

#pragma unroll
    for (int mf = 0; mf < 2; ++mf)
#pragma unroll
        for (int i = 0; i < 4; ++i) {
            float v = psum[mf][i];
            v += __shfl_xor(v, 1); v += __shfl_xor(v, 2);
            v += __shfl_xor(v, 4); v += __shfl_xor(v, 8);
            if ((lane & 15) == 0)
                sout[(size_t)c * BLn + b * 256 + it * 128 + w * 32 + mf * 16 + (lane >> 4) * 4 + i] = v;
        }
}

// transpose 4 matrices of 256x256 (src[c][d][e] fp32 -> dst[c][e][d] bf16)
__global__ void transpose256(const float* __restrict__ src, bf16* __restrict__ dst)
{
    const float* s = src + (size_t)blockIdx.x * 65536;
    bf16* d = dst + (size_t)blockIdx.x * 65536;
    __shared__ float t[32][33];
    const int tx = threadIdx.x & 31, ty8 = threadIdx.x >> 5;
    for (int bi = 0; bi < 8; ++bi)
        for (int bj = 0; bj < 8; ++bj) {
            __syncthreads();
            for (int r = ty8; r < 32; r += 8)
                t[r][tx] = s[(size_t)(bi * 32 + r) * 256 + bj * 32 + tx];
            __syncthreads();
            for (int r = ty8; r < 32; r += 8)
                stf(&d[(size_t)(bj * 32 + r) * 256 + bi * 32 + tx], t[tx][r]);
        }
}

__global__ void softmax256(const float* __restrict__ in, float* __restrict__ out)
{
    __shared__ float red[256];
    const int row = blockIdx.x, t = threadIdx.x;
    const float v = in[(size_t)row * 256 + t];
    red[t] = v; __syncthreads();
    for (int off = 128; off; off >>= 1) {
        if (t < off) red[t] = fmaxf(red[t], red[t + off]);
        __syncthreads();
    }
    const float mx = red[0]; __syncthreads();
    const float e = expf(v - mx);
    red[t] = e; __syncthreads();
    for (int off = 128; off; off >>= 1) {
        if (t < off) red[t] += red[t + off];
        __syncthreads();
    }
    out[(size_t)row * 256 + t] = e / red[0];
}

// new[c,b,d] for all 4 c in one pass over x (x read once per b)
__global__ __launch_bounds__(256)
void weighted_sum_kernel(const float* __restrict__ aa,
                         const bf16* __restrict__ x,
                         float* __restrict__ outnew)
{
    const int b = blockIdx.x, d = threadIdx.x;
    __shared__ float w4[4][Ln];
    for (int i = d; i < 4 * Ln; i += 256)
        w4[i >> 8][i & 255] = aa[((size_t)(i >> 8) * Bn + b) * Ln + (i & 255)];
    __syncthreads();
    float a0 = 0.f, a1 = 0.f, a2 = 0.f, a3 = 0.f;
    for (int l = 0; l < Ln; ++l) {
        const float xv = ldf(&x[((size_t)b * Ln + l) * Dn + d]);
        a0 += w4[0][l] * xv; a1 += w4[1][l] * xv;
        a2 += w4[2][l] * xv; a3 += w4[3][l] * xv;
    }
    outnew[((size_t)0 * Bn + b) * Dn + d] = a0;
    outnew[((size_t)1 * Bn + b) * Dn + d] = a1;
    outnew[((size_t)2 * Bn + b) * Dn + d] = a2;
    outnew[((size_t)3 * Bn + b) * Dn + d] = a3;
}

// pack conv filter rows (216) into 256x256 fp32 (rows 216+ zero)
__global__ void wpack_fill(const float* __restrict__ w0, const float* __restrict__ w1,
                           const float* __restrict__ w2, const float* __restrict__ w3,
                           float* __restrict__ wp)
{
    const int f = blockIdx.x;
    if (f < 4) {
        const int cnt[4]  = {4096, 9216, 16384, 25600};
        const int boff[4] = {0, 4096, 13312, 29696};
        const float* src = f == 0 ? w0 : f == 1 ? w1 : f == 2 ? w2 : w3;
        for (int i = threadIdx.x; i < cnt[f]; i += blockDim.x)
            wp[boff[f] + i] = src[i];
    } else {
        for (int i = threadIdx.x; i < 65536 - 55296; i += blockDim.x)
            wp[55296 + i] = 0.f;
    }
}

// nwd[b,row] = dot(new[c_of_row, b, :], wpack[row, :])
__global__ __launch_bounds__(256)
void nwd_kernel(const float* __restrict__ nw, const float* __restrict__ wp,
                float* __restrict__ nwd)
{
    const int b = blockIdx.x;
    __shared__ float ns[4][256];
    for (int i = threadIdx.x; i < 1024; i += 256)
        ns[i >> 8][i & 255] = nw[((size_t)((i >> 8) * Bn + b) << 8) + (i & 255)];
    __syncthreads();
    const int row = threadIdx.x;
    if (row < 216) {
        int f, base;
        if (row < 16)       { f = 0; base = 0; }
        else if (row < 52)  { f = 1; base = 16; }
        else if (row < 116) { f = 2; base = 52; }
        else                { f = 3; base = 116; }
        const int fs = f + 2, local = row - base;
        const int c = (local / fs) & 3;
        const float* wr = wp + (size_t)row * 256;
        float acc = 0.f;
        for (int k = 0; k < 256; ++k) acc += ns[c][k] * wr[k];
        nwd[b * 256 + row] = acc;
    }
}

// conv+relu+maxpool via decomposition (xwT now bf16)
__global__ __launch_bounds__(256)
void conv_combine(const bf16* __restrict__ xwT, const float* __restrict__ a,
                  const float* __restrict__ nwd, const float* __restrict__ cb,
                  float* __restrict__ pool, int fs, int base, int poff)
{
    const int b = blockIdx.x, tid = threadIdx.x;
    __shared__ float ash[4][256];
    __shared__ float basev[5];
    __shared__ float red[256];
    for (int i = tid; i < 1024; i += 256)
        ash[i >> 8][i & 255] = a[((size_t)((i >> 8) * Bn + b) << 8) + (i & 255)];
    if (tid < fs) {
        float s = cb[tid];
        for (int c = 0; c < 4; ++c)
            for (int kh = 0; kh < fs; ++kh)
                s += nwd[b * 256 + base + (tid * 4 + c) * fs + kh];
        basev[tid] = s;
    }
    __syncthreads();
    const int ni = Ln - fs + 1;
    const bf16* xb = xwT + ((size_t)b << 16);
    for (int o = 0; o < fs; ++o) {
        float best = 0.f;
        if (tid < ni) {
            float acc = basev[o];
            for (int c = 0; c < 4; ++c)
                for (int kh = 0; kh < fs; ++kh) {
                    const int row = base + (o * 4 + c) * fs + kh;
                    acc += ash[c][tid + kh] * ldf(&xb[(row << 8) + tid + kh]);
                }
            best = fmaxf(acc, 0.f);
        }
        red[tid] = best; __syncthreads();
        for (int off = 128; off; off >>= 1) {
            if (tid < off) red[tid] = fmaxf(red[tid], red[tid + off]);
            __syncthreads();
        }
        if (tid == 0) pool[b * 14 + poff + o] = red[0];
        __syncthreads();
    }
}

__global__ void fc_kernel(const float* __restrict__ pool, const float* __restrict__ fw,
                          const float* __restrict__ fb, float* __restrict__ out)
{
    const int i = threadIdx.x;           // 256 = B*OUT
    const int b = i >> 1, o = i & 1;
    float acc = fb[o];
#pragma unroll
    for (int f = 0; f < 14; ++f) acc += pool[b * 14 + f] * fw[o * 14 + f];
    out[i] = acc;
}

// ---------------------------------------------------------------------------
extern "C" void kernel_launch(void* const* d_in, const int* in_sizes, int n_in,
                              void* d_out, int out_size, void* d_ws, size_t ws_size,
                              hipStream_t stream)
{
    const int*   utt    = (const int*)  d_in[0];
    const float* emb    = (const float*)d_in[2];
    const float* w_ih0  = (const float*)d_in[3];
    const float* w_hh0  = (const float*)d_in[4];
    const float* b_ih0  = (const float*)d_in[5];
    const float* b_hh0  = (const float*)d_in[6];
    const float* w_ih1  = (const float*)d_in[7];
    const float* w_hh1  = (const float*)d_in[8];
    const float* b_ih1  = (const float*)d_in[9];
    const float* b_hh1  = (const float*)d_in[10];
    const float* att_w  = (const float*)d_in[11];
    const float* att_b  = (const float*)d_in[12];
    const float* att_wv2= (const float*)d_in[13];
    const float* att_bv = (const float*)d_in[14];
    const float* att_wv1= (const float*)d_in[15];
    const float* fc_w   = (const float*)d_in[16];
    const float* fc_b   = (const float*)d_in[17];
    const float* cw[4] = {(const float*)d_in[18], (const float*)d_in[20],
                          (const float*)d_in[22], (const float*)d_in[24]};
    const float* cb[4] = {(const float*)d_in[19], (const float*)d_in[21],
                          (const float*)d_in[23], (const float*)d_in[25]};

    float* ws = (float*)d_ws;
    bf16*  GX   = (bf16*)ws;                          // [0, 12.58M f32)
    bf16*  H1   = (bf16*)(ws + 12582912);             // [12.58M, 16.78M)
    bf16*  H2   = (bf16*)(ws + 16777216);             // [16.78M, 20.97M)
    bf16*  WT   = (bf16*)(ws + 20971520);             //   131,072 f32 slots
    float* WP   = ws + 20971520 + 131072;             //    65,536 f
    float* S    = WP + 65536;                         //   131,072 f
    float* Aa   = S + 131072;
    float* AL   = Aa + 131072;
    float* AAa  = AL + 131072;
    float* NEW_ = AAa + 131072;
    float* NWD  = NEW_ + 131072;                      //    32,768 f
    float* POOL = NWD + 32768;                        //     1,792 f
    bf16*  MATB = (bf16*)ws;   // fused-channel MAT, 67MB over dead GX+H1
    bf16*  XWT  = (bf16*)ws;   // bf16 xw output (16.7MB), aliases dead region

    // layer 0 + scan
    gemm_mfma<float, float, bf16, true, 0><<<dim3(6, 256), 256, 0, stream>>>(
        emb, w_ih0, b_ih0, GX, utt, BLn, 768, En);
    gru_scan_v9<<<dim3(Bn, 2), 768, 0, stream>>>(GX, w_hh0, b_hh0, H1);
    // layer 1 + scan
    gemm_mfma<bf16, float, bf16, false, 0><<<dim3(6, 256), 256, 0, stream>>>(
        H1, w_ih1, b_ih1, GX, nullptr, BLn, 768, Dn);
    gru_scan_v9<<<dim3(Bn, 2), 768, 0, stream>>>(GX, w_hh1, b_hh1, H2);

    // scalar attention: MATB = x @ [att_w^T stacked], fused 4-channel scores
    transpose256<<<4, 256, 0, stream>>>(att_w, WT);
    gemm_mfma<bf16, bf16, bf16, false, 0><<<dim3(8, 256), 256, 0, stream>>>(
        H2, WT, nullptr, MATB, nullptr, BLn, 1024, Dn);
    attn_score_mfma<<<dim3(2, Bn, Cn), 256, 0, stream>>>(H2, MATB, att_b, S);
    softmax256<<<Cn * Bn, 256, 0, stream>>>(S, Aa);

    // vector attention: fused GEMM+reduce (no gv materialization)
    transpose256<<<4, 256, 0, stream>>>(att_wv2, WT);
    hipMemsetAsync(AL, 0, (size_t)Cn * BLn * sizeof(float), stream);
    gv_gemm_reduce<<<dim3(8, 256), 256, 0, stream>>>(H2, WT, att_bv, att_wv1, AL);
    softmax256<<<Cn * Bn, 256, 0, stream>>>(AL, AAa);
    weighted_sum_kernel<<<Bn, 256, 0, stream>>>(AAa, H2, NEW_);

    // conv stage via xw GEMM decomposition (Cf never materialized)
    wpack_fill<<<5, 256, 0, stream>>>(cw[0], cw[1], cw[2], cw[3], WP);
    gemm_mfma<bf16, float, bf16, false, 1><<<dim3(2, 256), 256, 0, stream>>>(
        H2, WP, nullptr, XWT, nullptr, BLn, Dn, Dn);
    nwd_kernel<<<Bn, 256, 0, stream>>>(NEW_, WP, NWD);

    const int baserow[4] = {0, 16, 52, 116};
    const int poff[4]    = {0, 2, 5, 9};
    for (int f = 0; f < 4; ++f)
        conv_combine<<<Bn, 256, 0, stream>>>(XWT, Aa, NWD, cb[f], POOL, f + 2, baserow[f], poff[f]);

    fc_kernel<<<1, 256, 0, stream>>>(POOL, fc_w, fc_b, (float*)d_out);
}

// Round 15
// 1089.945 us; speedup vs baseline: 1.0779x; 1.0054x over previous
//
#include <hip/hip_runtime.h>
#include <hip/hip_bf16.h>
#include <hip/hip_fp16.h>

#define Bn  128
#define Ln  256
#define En  300
#define Hn  128
#define Cn  4
#define Dn  256     // 2H
#define G3n 384     // 3H
#define BLn (Bn * Ln)   // 32768

typedef __hip_bfloat16 bf16;
typedef short s16x8 __attribute__((ext_vector_type(8)));
typedef float f32x4 __attribute__((ext_vector_type(4)));
typedef _Float16 h16x2 __attribute__((ext_vector_type(2)));

__device__ __forceinline__ float ldf(const float* p) { return *p; }
__device__ __forceinline__ float ldf(const bf16* p)  { return __bfloat162float(*p); }
__device__ __forceinline__ void stf(float* p, float v) { *p = v; }
__device__ __forceinline__ void stf(bf16* p, float v)  { *p = __float2bfloat16(v); }

__device__ __forceinline__ ushort f2bf(float f) {
    bf16 h = __float2bfloat16(f);
    return *reinterpret_cast<ushort*>(&h);
}
__device__ __forceinline__ float bfu(ushort x) {
    unsigned t = ((unsigned)x) << 16;
    return __builtin_bit_cast(float, t);
}

#if __has_builtin(__builtin_amdgcn_fdot2)
__device__ __forceinline__ float dot2f(h16x2 w, h16x2 h, float c) {
    return __builtin_amdgcn_fdot2(w, h, c, false);
}
#else
__device__ __forceinline__ float dot2f(h16x2 w, h16x2 h, float c) {
    return fmaf((float)w[0], (float)h[0], fmaf((float)w[1], (float)h[1], c));
}
#endif
#define BCH(x) __builtin_bit_cast(h16x2, x)

// 16B-or-8B load of 4 values, fp32 or bf16 source
__device__ __forceinline__ float4 ld4f(const float* p) { return *(const float4*)p; }
__device__ __forceinline__ float4 ld4f(const bf16* p) {
    ushort4 u = *(const ushort4*)p;
    return make_float4(bfu(u.x), bfu(u.y), bfu(u.z), bfu(u.w));
}

// ---------------------------------------------------------------------------
// MFMA bf16 GEMM: C[M,N] = A[M,K] * W^T + bias   (W is (N,K) row-major)
//   AT/WTp in {float,bf16}; GATHER: A row m = A[gidx[m]*K ..]
//   SM==1: store C[(m>>8),n,(m&255)]
// ---------------------------------------------------------------------------
template<class AT, class WTp, class OT, bool GATHER, int SM>
__global__ __launch_bounds__(256)
void gemm_mfma(const AT* __restrict__ A, const WTp* __restrict__ W,
               const float* __restrict__ bias, OT* __restrict__ Cout,
               const int* __restrict__ gidx, int M, int N, int K)
{
    __shared__ ushort Asm[128 * 40];
    __shared__ ushort Bsm[128 * 40];
    const int bm = blockIdx.y * 128, bn = blockIdx.x * 128;
    const int tid = threadIdx.x;
    const int lane = tid & 63, w = tid >> 6, wr = w >> 1, wc = w & 1;

    const AT* arow[4];
    const WTp* brow[4];
#pragma unroll
    for (int u = 0; u < 4; ++u) {
        const int idx = tid + u * 256;
        const int m = idx >> 3;
        arow[u] = A + (size_t)(GATHER ? gidx[bm + m] : (bm + m)) * K;
        brow[u] = W + (size_t)(bn + m) * K;
    }

    f32x4 acc[4][4] = {};
    const int nkt = (K + 31) >> 5;
    for (int kt = 0; kt < nkt; ++kt) {
        const int k0 = kt << 5;
#pragma unroll
        for (int u = 0; u < 4; ++u) {
            const int idx = tid + u * 256;
            const int m = idx >> 3, kq = idx & 7;
            const int kb = k0 + kq * 4;
            float4 v, q;
            if (kb + 4 <= K) {
                v = ld4f(arow[u] + kb);
                q = ld4f(brow[u] + kb);
            } else {
                v.x = kb + 0 < K ? ldf(&arow[u][kb + 0]) : 0.f;
                v.y = kb + 1 < K ? ldf(&arow[u][kb + 1]) : 0.f;
                v.z = kb + 2 < K ? ldf(&arow[u][kb + 2]) : 0.f;
                v.w = kb + 3 < K ? ldf(&arow[u][kb + 3]) : 0.f;
                q.x = kb + 0 < K ? ldf(&brow[u][kb + 0]) : 0.f;
                q.y = kb + 1 < K ? ldf(&brow[u][kb + 1]) : 0.f;
                q.z = kb + 2 < K ? ldf(&brow[u][kb + 2]) : 0.f;
                q.w = kb + 3 < K ? ldf(&brow[u][kb + 3]) : 0.f;
            }
            *(ushort4*)&Asm[m * 40 + kq * 4] =
                make_ushort4(f2bf(v.x), f2bf(v.y), f2bf(v.z), f2bf(v.w));
            *(ushort4*)&Bsm[m * 40 + kq * 4] =
                make_ushort4(f2bf(q.x), f2bf(q.y), f2bf(q.z), f2bf(q.w));
        }
        __syncthreads();
        s16x8 af[4], bfr[4];
#pragma unroll
        for (int t = 0; t < 4; ++t) {
            af[t]  = *(const s16x8*)&Asm[(wr * 64 + t * 16 + (lane & 15)) * 40 + (lane >> 4) * 8];
            bfr[t] = *(const s16x8*)&Bsm[(wc * 64 + t * 16 + (lane & 15)) * 40 + (lane >> 4) * 8];
        }
#pragma unroll
        for (int mf = 0; mf < 4; ++mf)
#pragma unroll
            for (int nf = 0; nf < 4; ++nf)
                acc[mf][nf] = __builtin_amdgcn_mfma_f32_16x16x32_bf16(
                    af[mf], bfr[nf], acc[mf][nf], 0, 0, 0);
        __syncthreads();
    }

#pragma unroll
    for (int mf = 0; mf < 4; ++mf)
#pragma unroll
        for (int nf = 0; nf < 4; ++nf) {
            const int col = bn + wc * 64 + nf * 16 + (lane & 15);
            const float bv_ = bias ? bias[col] : 0.f;
#pragma unroll
            for (int i = 0; i < 4; ++i) {
                const int row = bm + wr * 64 + mf * 16 + (lane >> 4) * 4 + i;
                const float v = acc[mf][nf][i] + bv_;
                if (SM == 1)
                    stf(&Cout[((size_t)(row >> 8) * N + col) * 256 + (row & 255)], v);
                else
                    stf(&Cout[(size_t)row * N + col], v);
            }
        }
}

// ---------------------------------------------------------------------------
// gv GEMM + fused sigmoid-weighted row reduction. AL zeroed before launch.
// ---------------------------------------------------------------------------
__global__ __launch_bounds__(256)
void gv_gemm_reduce(const bf16* __restrict__ A, const bf16* __restrict__ W,
                    const float* __restrict__ bv, const float* __restrict__ wv1,
                    float* __restrict__ al)
{
    __shared__ ushort Asm[128 * 40];
    __shared__ ushort Bsm[128 * 40];
    const int bm = blockIdx.y * 128, bn = blockIdx.x * 128;
    const int tid = threadIdx.x;
    const int lane = tid & 63, w = tid >> 6, wr = w >> 1, wc = w & 1;

    f32x4 acc[4][4] = {};
    for (int kt = 0; kt < 8; ++kt) {
        const int k0 = kt << 5;
#pragma unroll
        for (int u = 0; u < 2; ++u) {
            const int idx = tid + u * 256;
            const int m = idx >> 2, q = idx & 3;
            *(s16x8*)&Asm[m * 40 + q * 8] =
                *(const s16x8*)&A[(size_t)(bm + m) * 256 + k0 + q * 8];
            *(s16x8*)&Bsm[m * 40 + q * 8] =
                *(const s16x8*)&W[(size_t)(bn + m) * 256 + k0 + q * 8];
        }
        __syncthreads();
        s16x8 af[4], bfr[4];
#pragma unroll
        for (int t = 0; t < 4; ++t) {
            af[t]  = *(const s16x8*)&Asm[(wr * 64 + t * 16 + (lane & 15)) * 40 + (lane >> 4) * 8];
            bfr[t] = *(const s16x8*)&Bsm[(wc * 64 + t * 16 + (lane & 15)) * 40 + (lane >> 4) * 8];
        }
#pragma unroll
        for (int mf = 0; mf < 4; ++mf)
#pragma unroll
            for (int nf = 0; nf < 4; ++nf)
                acc[mf][nf] = __builtin_amdgcn_mfma_f32_16x16x32_bf16(
                    af[mf], bfr[nf], acc[mf][nf], 0, 0, 0);
        __syncthreads();
    }

    float bb[4], wv[4];
#pragma unroll
    for (int nf = 0; nf < 4; ++nf) {
        const int col = bn + wc * 64 + nf * 16 + (lane & 15);
        bb[nf] = bv[col];
        wv[nf] = wv1[col];
    }
    const size_t cbase = (size_t)(bn >> 8) * BLn;
#pragma unroll
    for (int mf = 0; mf < 4; ++mf)
#pragma unroll
        for (int i = 0; i < 4; ++i) {
            float p = 0.f;
#pragma unroll
            for (int nf = 0; nf < 4; ++nf)
                p += wv[nf] / (1.f + expf(-(acc[mf][nf][i] + bb[nf])));
            p += __shfl_xor(p, 1); p += __shfl_xor(p, 2);
            p += __shfl_xor(p, 4); p += __shfl_xor(p, 8);
            if ((lane & 15) == 0) {
                const int row = bm + wr * 64 + mf * 16 + (lane >> 4) * 4 + i;
                atomicAdd(&al[cbase + row], p);
            }
        }
}

// ---------------------------------------------------------------------------
// GRU scan v11: v9's k-split, but the two k-halves of a row are ADJACENT
// LANES (t = 2r+half) -> partials combine via shfl_xor(1), killing the
// part[] buffer, its LDS traffic, and one of v9's 3 barriers. Pair
// addresses differ by 128B = same bank, different row = 2-way (free, m136).
// ---------------------------------------------------------------------------
__global__ __launch_bounds__(768, 1)
void gru_scan_v11(const bf16* __restrict__ gx, const float* __restrict__ w_hh,
                  const float* __restrict__ b_hh, bf16* __restrict__ out)
{
    const int b = blockIdx.x, dir = blockIdx.y;
    const int t = threadIdx.x;
    const int r = t >> 1, half = t & 1;      // gate row 0..383, k-half
    __shared__ __align__(16) ushort wl[384 * 136];   // 272B rows, 104448 B
    __shared__ __align__(16) ushort hp16[128];       // h as f16
    __shared__ float h_sh[128];
    __shared__ float rs[128], zs[128], gxn[128], ghn[128];

    const float* wbase = w_hh + (size_t)dir * G3n * Hn;
    for (int idx = t; idx < G3n * 64; idx += 768) {
        const int row = idx >> 6, k2 = idx & 63;
        const float2 v = *(const float2*)(wbase + row * Hn + 2 * k2);
        h16x2 p; p[0] = (_Float16)v.x; p[1] = (_Float16)v.y;
        *(h16x2*)&wl[row * 136 + 2 * k2] = p;
    }
    if (t < 128) { hp16[t] = 0; h_sh[t] = 0.f; }
    const float bh = b_hh[dir * G3n + r];
    __syncthreads();

    const size_t g0 = (size_t)b * Ln * 768 + dir * G3n + r
                      + (dir ? (size_t)(Ln - 1) * 768 : 0);
    const long gstep = dir ? -768L : 768L;
    float gcur = 0.f, gnx = 0.f;
    if (!half) { gcur = ldf(&gx[g0]); gnx = ldf(&gx[g0 + gstep]); }

    const ushort* wrow  = &wl[r * 136 + half * 64];  // this half's 64 weights
    const ushort* hbase = &hp16[half * 64];          // this half's 64 h vals

    for (int s = 0; s < Ln; ++s) {
        const int tt = dir ? (Ln - 1 - s) : s;
        float gn2 = 0.f;
        if (!half && s + 2 < Ln) gn2 = ldf(&gx[g0 + (long)(s + 2) * gstep]);

        float a0 = 0.f, a1 = 0.f, a2 = 0.f, a3 = 0.f;
#pragma unroll
        for (int j = 0; j < 8; ++j) {
            const float4 wv = *(const float4*)&wrow[8 * j];
            const float4 hv = *(const float4*)&hbase[8 * j];
            a0 = dot2f(BCH(wv.x), BCH(hv.x), a0);
            a1 = dot2f(BCH(wv.y), BCH(hv.y), a1);
            a2 = dot2f(BCH(wv.z), BCH(hv.z), a2);
            a3 = dot2f(BCH(wv.w), BCH(hv.w), a3);
        }
        float acc = (a0 + a1) + (a2 + a3);
        acc += __shfl_xor(acc, 1);           // combine k-halves (same wave)

        if (!half) {
            const float tot = acc + bh;
            if (r < 128)      rs[r]       = 1.f / (1.f + expf(-(gcur + tot)));
            else if (r < 256) zs[r - 128] = 1.f / (1.f + expf(-(gcur + tot)));
            else { gxn[r - 256] = gcur; ghn[r - 256] = tot; }
        }
        __syncthreads();

        if (t < 128) {
            const int j = t;
            const float nn = tanhf(gxn[j] + rs[j] * ghn[j]);
            const float hnew = (1.f - zs[j]) * nn + zs[j] * h_sh[j];
            h_sh[j] = hnew;
            const _Float16 hf = (_Float16)hnew;
            hp16[j] = __builtin_bit_cast(ushort, hf);
            out[((size_t)b * Ln + tt) * Dn + dir * Hn + j] = __float2bfloat16(hnew);
        }
        __syncthreads();
        if (!half) { gcur = gnx; gnx = gn2; }
    }
}

// ---------------------------------------------------------------------------
// attn score, MFMA, fused channels: grid (2, B, C); mat row stride 1024.
// ---------------------------------------------------------------------------
__global__ __launch_bounds__(256)
void attn_score_mfma(const bf16* __restrict__ x, const bf16* __restrict__ matb,
                     const float* __restrict__ attb, float* __restrict__ sout)
{
    const int it = blockIdx.x, b = blockIdx.y, c = blockIdx.z;
    const bf16* A  = x + ((size_t)b * 256 + it * 128) * 256;
    const bf16* Bm = matb + (size_t)b * 256 * 1024 + c * 256;
    __shared__ ushort Xs[128 * 40];
    __shared__ ushort Ms[128 * 40];
    const int tid = threadIdx.x, lane = tid & 63, w = tid >> 6;
    const float bc = attb[c];
    float psum[2][4] = {};

    for (int jt = 0; jt < 2; ++jt) {
        f32x4 acc[2][8] = {};
        for (int kt = 0; kt < 8; ++kt) {
            const int k0 = kt << 5;
#pragma unroll
            for (int u = 0; u < 2; ++u) {
                const int idx = tid + u * 256;
                const int m = idx >> 2, q = idx & 3;
                *(s16x8*)&Xs[m * 40 + q * 8] =
                    *(const s16x8*)&A[(size_t)m * 256 + k0 + q * 8];
                *(s16x8*)&Ms[m * 40 + q * 8] =
                    *(const s16x8*)&Bm[(size_t)(jt * 128 + m) * 1024 + k0 + q * 8];
            }
            __syncthreads();
            s16x8 af[2], bfr[8];
#pragma unroll
            for (int t = 0; t < 2; ++t)
                af[t] = *(const s16x8*)&Xs[(w * 32 + t * 16 + (lane & 15)) * 40 + (lane >> 4) * 8];
#pragma unroll
            for (int t = 0; t < 8; ++t)
                bfr[t] = *(const s16x8*)&Ms[(t * 16 + (lane & 15)) * 40 + (lane >> 4) * 8];
#pragma unroll
            for (int mf = 0; mf < 2; ++mf)
#pragma unroll
                for (int nf = 0; nf < 8; ++nf)
                    acc[mf][nf] = __builtin_amdgcn_mfma_f32_16x16x32_bf16(
                        af[mf], bfr[nf], acc[mf][nf], 0, 0, 0);
            __syncthreads();
        }
#pragma unroll
        for (int mf = 0; mf < 2; ++mf)
#pragma unroll
            for (int nf = 0; nf < 8; ++nf)
#pragma unroll
                for (int i = 0; i < 4; ++i)
                    psum[mf][i] += tanhf(acc[mf][nf][i] + bc);
    }

#pragma unroll
    for (int mf = 0; mf < 2; ++mf)
#pragma unroll
        for (int i = 0; i < 4; ++i) {
            float v = psum[mf][i];
            v += __shfl_xor(v, 1); v += __shfl_xor(v, 2);
            v += __shfl_xor(v, 4); v += __shfl_xor(v, 8);
            if ((lane & 15) == 0)
                sout[(size_t)c * BLn + b * 256 + it * 128 + w * 32 + mf * 16 + (lane >> 4) * 4 + i] = v;
        }
}

// transpose 4 matrices of 256x256 (src[c][d][e] fp32 -> dst[c][e][d] bf16)
__global__ void transpose256(const float* __restrict__ src, bf16* __restrict__ dst)
{
    const float* s = src + (size_t)blockIdx.x * 65536;
    bf16* d = dst + (size_t)blockIdx.x * 65536;
    __shared__ float t[32][33];
    const int tx = threadIdx.x & 31, ty8 = threadIdx.x >> 5;
    for (int bi = 0; bi < 8; ++bi)
        for (int bj = 0; bj < 8; ++bj) {
            __syncthreads();
            for (int r = ty8; r < 32; r += 8)
                t[r][tx] = s[(size_t)(bi * 32 + r) * 256 + bj * 32 + tx];
            __syncthreads();
            for (int r = ty8; r < 32; r += 8)
                stf(&d[(size_t)(bj * 32 + r) * 256 + bi * 32 + tx], t[tx][r]);
        }
}

__global__ void softmax256(const float* __restrict__ in, float* __restrict__ out)
{
    __shared__ float red[256];
    const int row = blockIdx.x, t = threadIdx.x;
    const float v = in[(size_t)row * 256 + t];
    red[t] = v; __syncthreads();
    for (int off = 128; off; off >>= 1) {
        if (t < off) red[t] = fmaxf(red[t], red[t + off]);
        __syncthreads();
    }
    const float mx = red[0]; __syncthreads();
    const float e = expf(v - mx);
    red[t] = e; __syncthreads();
    for (int off = 128; off; off >>= 1) {
        if (t < off) red[t] += red[t + off];
        __syncthreads();
    }
    out[(size_t)row * 256 + t] = e / red[0];
}

// new[c,b,d] for all 4 c in one pass over x (x read once per b)
__global__ __launch_bounds__(256)
void weighted_sum_kernel(const float* __restrict__ aa,
                         const bf16* __restrict__ x,
                         float* __restrict__ outnew)
{
    const int b = blockIdx.x, d = threadIdx.x;
    __shared__ float w4[4][Ln];
    for (int i = d; i < 4 * Ln; i += 256)
        w4[i >> 8][i & 255] = aa[((size_t)(i >> 8) * Bn + b) * Ln + (i & 255)];
    __syncthreads();
    float a0 = 0.f, a1 = 0.f, a2 = 0.f, a3 = 0.f;
    for (int l = 0; l < Ln; ++l) {
        const float xv = ldf(&x[((size_t)b * Ln + l) * Dn + d]);
        a0 += w4[0][l] * xv; a1 += w4[1][l] * xv;
        a2 += w4[2][l] * xv; a3 += w4[3][l] * xv;
    }
    outnew[((size_t)0 * Bn + b) * Dn + d] = a0;
    outnew[((size_t)1 * Bn + b) * Dn + d] = a1;
    outnew[((size_t)2 * Bn + b) * Dn + d] = a2;
    outnew[((size_t)3 * Bn + b) * Dn + d] = a3;
}

// pack conv filter rows (216) into 256x256 fp32 (rows 216+ zero)
__global__ void wpack_fill(const float* __restrict__ w0, const float* __restrict__ w1,
                           const float* __restrict__ w2, const float* __restrict__ w3,
                           float* __restrict__ wp)
{
    const int f = blockIdx.x;
    if (f < 4) {
        const int cnt[4]  = {4096, 9216, 16384, 25600};
        const int boff[4] = {0, 4096, 13312, 29696};
        const float* src = f == 0 ? w0 : f == 1 ? w1 : f == 2 ? w2 : w3;
        for (int i = threadIdx.x; i < cnt[f]; i += blockDim.x)
            wp[boff[f] + i] = src[i];
    } else {
        for (int i = threadIdx.x; i < 65536 - 55296; i += blockDim.x)
            wp[55296 + i] = 0.f;
    }
}

// nwd[b,row] = dot(new[c_of_row, b, :], wpack[row, :])
__global__ __launch_bounds__(256)
void nwd_kernel(const float* __restrict__ nw, const float* __restrict__ wp,
                float* __restrict__ nwd)
{
    const int b = blockIdx.x;
    __shared__ float ns[4][256];
    for (int i = threadIdx.x; i < 1024; i += 256)
        ns[i >> 8][i & 255] = nw[((size_t)((i >> 8) * Bn + b) << 8) + (i & 255)];
    __syncthreads();
    const int row = threadIdx.x;
    if (row < 216) {
        int f, base;
        if (row < 16)       { f = 0; base = 0; }
        else if (row < 52)  { f = 1; base = 16; }
        else if (row < 116) { f = 2; base = 52; }
        else                { f = 3; base = 116; }
        const int fs = f + 2, local = row - base;
        const int c = (local / fs) & 3;
        const float* wr = wp + (size_t)row * 256;
        float acc = 0.f;
        for (int k = 0; k < 256; ++k) acc += ns[c][k] * wr[k];
        nwd[b * 256 + row] = acc;
    }
}

// conv+relu+maxpool, ALL 4 filter sizes in one launch: grid (B, 4).
// (4 serial 128-block launches each half-filled the 256 CUs.)
__global__ __launch_bounds__(256)
void conv_combine_all(const bf16* __restrict__ xwT, const float* __restrict__ a,
                      const float* __restrict__ nwd,
                      const float* __restrict__ cb0, const float* __restrict__ cb1,
                      const float* __restrict__ cb2, const float* __restrict__ cb3,
                      float* __restrict__ pool)
{
    const int b = blockIdx.x, f = blockIdx.y, tid = threadIdx.x;
    const int fs = f + 2;
    const int base = (f == 0) ? 0 : (f == 1) ? 16 : (f == 2) ? 52 : 116;
    const int poff = (f == 0) ? 0 : (f == 1) ? 2 : (f == 2) ? 5 : 9;
    const float* cb = (f == 0) ? cb0 : (f == 1) ? cb1 : (f == 2) ? cb2 : cb3;

    __shared__ float ash[4][256];
    __shared__ float basev[5];
    __shared__ float red[256];
    for (int i = tid; i < 1024; i += 256)
        ash[i >> 8][i & 255] = a[((size_t)((i >> 8) * Bn + b) << 8) + (i & 255)];
    if (tid < fs) {
        float s = cb[tid];
        for (int c = 0; c < 4; ++c)
            for (int kh = 0; kh < fs; ++kh)
                s += nwd[b * 256 + base + (tid * 4 + c) * fs + kh];
        basev[tid] = s;
    }
    __syncthreads();
    const int ni = Ln - fs + 1;
    const bf16* xb = xwT + ((size_t)b << 16);
    for (int o = 0; o < fs; ++o) {
        float best = 0.f;
        if (tid < ni) {
            float acc = basev[o];
            for (int c = 0; c < 4; ++c)
                for (int kh = 0; kh < fs; ++kh) {
                    const int row = base + (o * 4 + c) * fs + kh;
                    acc += ash[c][tid + kh] * ldf(&xb[(row << 8) + tid + kh]);
                }
            best = fmaxf(acc, 0.f);
        }
        red[tid] = best; __syncthreads();
        for (int off = 128; off; off >>= 1) {
            if (tid < off) red[tid] = fmaxf(red[tid], red[tid + off]);
            __syncthreads();
        }
        if (tid == 0) pool[b * 14 + poff + o] = red[0];
        __syncthreads();
    }
}

__global__ void fc_kernel(const float* __restrict__ pool, const float* __restrict__ fw,
                          const float* __restrict__ fb, float* __restrict__ out)
{
    const int i = threadIdx.x;           // 256 = B*OUT
    const int b = i >> 1, o = i & 1;
    float acc = fb[o];
#pragma unroll
    for (int f = 0; f < 14; ++f) acc += pool[b * 14 + f] * fw[o * 14 + f];
    out[i] = acc;
}

// ---------------------------------------------------------------------------
extern "C" void kernel_launch(void* const* d_in, const int* in_sizes, int n_in,
                              void* d_out, int out_size, void* d_ws, size_t ws_size,
                              hipStream_t stream)
{
    const int*   utt    = (const int*)  d_in[0];
    const float* emb    = (const float*)d_in[2];
    const float* w_ih0  = (const float*)d_in[3];
    const float* w_hh0  = (const float*)d_in[4];
    const float* b_ih0  = (const float*)d_in[5];
    const float* b_hh0  = (const float*)d_in[6];
    const float* w_ih1  = (const float*)d_in[7];
    const float* w_hh1  = (const float*)d_in[8];
    const float* b_ih1  = (const float*)d_in[9];
    const float* b_hh1  = (const float*)d_in[10];
    const float* att_w  = (const float*)d_in[11];
    const float* att_b  = (const float*)d_in[12];
    const float* att_wv2= (const float*)d_in[13];
    const float* att_bv = (const float*)d_in[14];
    const float* att_wv1= (const float*)d_in[15];
    const float* fc_w   = (const float*)d_in[16];
    const float* fc_b   = (const float*)d_in[17];
    const float* cw[4] = {(const float*)d_in[18], (const float*)d_in[20],
                          (const float*)d_in[22], (const float*)d_in[24]};
    const float* cb[4] = {(const float*)d_in[19], (const float*)d_in[21],
                          (const float*)d_in[23], (const float*)d_in[25]};

    float* ws = (float*)d_ws;
    bf16*  GX   = (bf16*)ws;                          // [0, 12.58M f32)
    bf16*  H1   = (bf16*)(ws + 12582912);             // [12.58M, 16.78M)
    bf16*  H2   = (bf16*)(ws + 16777216);             // [16.78M, 20.97M)
    bf16*  WT   = (bf16*)(ws + 20971520);             //   131,072 f32 slots
    float* WP   = ws + 20971520 + 131072;             //    65,536 f
    float* S    = WP + 65536;                         //   131,072 f
    float* Aa   = S + 131072;
    float* AL   = Aa + 131072;
    float* AAa  = AL + 131072;
    float* NEW_ = AAa + 131072;
    float* NWD  = NEW_ + 131072;                      //    32,768 f
    float* POOL = NWD + 32768;                        //     1,792 f
    bf16*  MATB = (bf16*)ws;   // fused-channel MAT, 67MB over dead GX+H1
    bf16*  XWT  = (bf16*)ws;   // bf16 xw output (16.7MB), aliases dead region

    // layer 0 + scan
    gemm_mfma<float, float, bf16, true, 0><<<dim3(6, 256), 256, 0, stream>>>(
        emb, w_ih0, b_ih0, GX, utt, BLn, 768, En);
    gru_scan_v11<<<dim3(Bn, 2), 768, 0, stream>>>(GX, w_hh0, b_hh0, H1);
    // layer 1 + scan
    gemm_mfma<bf16, float, bf16, false, 0><<<dim3(6, 256), 256, 0, stream>>>(
        H1, w_ih1, b_ih1, GX, nullptr, BLn, 768, Dn);
    gru_scan_v11<<<dim3(Bn, 2), 768, 0, stream>>>(GX, w_hh1, b_hh1, H2);

    // scalar attention: MATB = x @ [att_w^T stacked], fused 4-channel scores
    transpose256<<<4, 256, 0, stream>>>(att_w, WT);
    gemm_mfma<bf16, bf16, bf16, false, 0><<<dim3(8, 256), 256, 0, stream>>>(
        H2, WT, nullptr, MATB, nullptr, BLn, 1024, Dn);
    attn_score_mfma<<<dim3(2, Bn, Cn), 256, 0, stream>>>(H2, MATB, att_b, S);
    softmax256<<<Cn * Bn, 256, 0, stream>>>(S, Aa);

    // vector attention: fused GEMM+reduce (no gv materialization)
    transpose256<<<4, 256, 0, stream>>>(att_wv2, WT);
    hipMemsetAsync(AL, 0, (size_t)Cn * BLn * sizeof(float), stream);
    gv_gemm_reduce<<<dim3(8, 256), 256, 0, stream>>>(H2, WT, att_bv, att_wv1, AL);
    softmax256<<<Cn * Bn, 256, 0, stream>>>(AL, AAa);
    weighted_sum_kernel<<<Bn, 256, 0, stream>>>(AAa, H2, NEW_);

    // conv stage via xw GEMM decomposition (Cf never materialized)
    wpack_fill<<<5, 256, 0, stream>>>(cw[0], cw[1], cw[2], cw[3], WP);
    gemm_mfma<bf16, float, bf16, false, 1><<<dim3(2, 256), 256, 0, stream>>>(
        H2, WP, nullptr, XWT, nullptr, BLn, Dn, Dn);
    nwd_kernel<<<Bn, 256, 0, stream>>>(NEW_, WP, NWD);

    conv_combine_all<<<dim3(Bn, 4), 256, 0, stream>>>(
        XWT, Aa, NWD, cb[0], cb[1], cb[2], cb[3], POOL);

    fc_kernel<<<1, 256, 0, stream>>>(POOL, fc_w, fc_b, (float*)d_out);
}

// Round 16
// 1051.932 us; speedup vs baseline: 1.1169x; 1.0361x over previous
//
#include <hip/hip_runtime.h>
#include <hip/hip_bf16.h>
#include <hip/hip_fp16.h>

#define Bn  128
#define Ln  256
#define En  300
#define Hn  128
#define Cn  4
#define Dn  256     // 2H
#define G3n 384     // 3H
#define BLn (Bn * Ln)   // 32768

typedef __hip_bfloat16 bf16;
typedef short s16x8 __attribute__((ext_vector_type(8)));
typedef float f32x4 __attribute__((ext_vector_type(4)));
typedef _Float16 h16x2 __attribute__((ext_vector_type(2)));

__device__ __forceinline__ float ldf(const float* p) { return *p; }
__device__ __forceinline__ float ldf(const bf16* p)  { return __bfloat162float(*p); }
__device__ __forceinline__ void stf(float* p, float v) { *p = v; }
__device__ __forceinline__ void stf(bf16* p, float v)  { *p = __float2bfloat16(v); }

__device__ __forceinline__ ushort f2bf(float f) {
    bf16 h = __float2bfloat16(f);
    return *reinterpret_cast<ushort*>(&h);
}
__device__ __forceinline__ float bfu(ushort x) {
    unsigned t = ((unsigned)x) << 16;
    return __builtin_bit_cast(float, t);
}

#if __has_builtin(__builtin_amdgcn_fdot2)
__device__ __forceinline__ float dot2f(h16x2 w, h16x2 h, float c) {
    return __builtin_amdgcn_fdot2(w, h, c, false);
}
#else
__device__ __forceinline__ float dot2f(h16x2 w, h16x2 h, float c) {
    return fmaf((float)w[0], (float)h[0], fmaf((float)w[1], (float)h[1], c));
}
#endif
#define BCH(x) __builtin_bit_cast(h16x2, x)

// 16B-or-8B load of 4 values, fp32 or bf16 source
__device__ __forceinline__ float4 ld4f(const float* p) { return *(const float4*)p; }
__device__ __forceinline__ float4 ld4f(const bf16* p) {
    ushort4 u = *(const ushort4*)p;
    return make_float4(bfu(u.x), bfu(u.y), bfu(u.z), bfu(u.w));
}

// ---------------------------------------------------------------------------
// MFMA bf16 GEMM: C[M,N] = A[M,K] * W^T + bias   (W is (N,K) row-major)
//   AT/WTp in {float,bf16}; GATHER: A row m = A[gidx[m]*K ..]
//   SM==1: store C[(m>>8),n,(m&255)]
// ---------------------------------------------------------------------------
template<class AT, class WTp, class OT, bool GATHER, int SM>
__global__ __launch_bounds__(256)
void gemm_mfma(const AT* __restrict__ A, const WTp* __restrict__ W,
               const float* __restrict__ bias, OT* __restrict__ Cout,
               const int* __restrict__ gidx, int M, int N, int K)
{
    __shared__ ushort Asm[128 * 40];
    __shared__ ushort Bsm[128 * 40];
    const int bm = blockIdx.y * 128, bn = blockIdx.x * 128;
    const int tid = threadIdx.x;
    const int lane = tid & 63, w = tid >> 6, wr = w >> 1, wc = w & 1;

    const AT* arow[4];
    const WTp* brow[4];
#pragma unroll
    for (int u = 0; u < 4; ++u) {
        const int idx = tid + u * 256;
        const int m = idx >> 3;
        arow[u] = A + (size_t)(GATHER ? gidx[bm + m] : (bm + m)) * K;
        brow[u] = W + (size_t)(bn + m) * K;
    }

    f32x4 acc[4][4] = {};
    const int nkt = (K + 31) >> 5;
    for (int kt = 0; kt < nkt; ++kt) {
        const int k0 = kt << 5;
#pragma unroll
        for (int u = 0; u < 4; ++u) {
            const int idx = tid + u * 256;
            const int m = idx >> 3, kq = idx & 7;
            const int kb = k0 + kq * 4;
            float4 v, q;
            if (kb + 4 <= K) {
                v = ld4f(arow[u] + kb);
                q = ld4f(brow[u] + kb);
            } else {
                v.x = kb + 0 < K ? ldf(&arow[u][kb + 0]) : 0.f;
                v.y = kb + 1 < K ? ldf(&arow[u][kb + 1]) : 0.f;
                v.z = kb + 2 < K ? ldf(&arow[u][kb + 2]) : 0.f;
                v.w = kb + 3 < K ? ldf(&arow[u][kb + 3]) : 0.f;
                q.x = kb + 0 < K ? ldf(&brow[u][kb + 0]) : 0.f;
                q.y = kb + 1 < K ? ldf(&brow[u][kb + 1]) : 0.f;
                q.z = kb + 2 < K ? ldf(&brow[u][kb + 2]) : 0.f;
                q.w = kb + 3 < K ? ldf(&brow[u][kb + 3]) : 0.f;
            }
            *(ushort4*)&Asm[m * 40 + kq * 4] =
                make_ushort4(f2bf(v.x), f2bf(v.y), f2bf(v.z), f2bf(v.w));
            *(ushort4*)&Bsm[m * 40 + kq * 4] =
                make_ushort4(f2bf(q.x), f2bf(q.y), f2bf(q.z), f2bf(q.w));
        }
        __syncthreads();
        s16x8 af[4], bfr[4];
#pragma unroll
        for (int t = 0; t < 4; ++t) {
            af[t]  = *(const s16x8*)&Asm[(wr * 64 + t * 16 + (lane & 15)) * 40 + (lane >> 4) * 8];
            bfr[t] = *(const s16x8*)&Bsm[(wc * 64 + t * 16 + (lane & 15)) * 40 + (lane >> 4) * 8];
        }
#pragma unroll
        for (int mf = 0; mf < 4; ++mf)
#pragma unroll
            for (int nf = 0; nf < 4; ++nf)
                acc[mf][nf] = __builtin_amdgcn_mfma_f32_16x16x32_bf16(
                    af[mf], bfr[nf], acc[mf][nf], 0, 0, 0);
        __syncthreads();
    }

#pragma unroll
    for (int mf = 0; mf < 4; ++mf)
#pragma unroll
        for (int nf = 0; nf < 4; ++nf) {
            const int col = bn + wc * 64 + nf * 16 + (lane & 15);
            const float bv_ = bias ? bias[col] : 0.f;
#pragma unroll
            for (int i = 0; i < 4; ++i) {
                const int row = bm + wr * 64 + mf * 16 + (lane >> 4) * 4 + i;
                const float v = acc[mf][nf][i] + bv_;
                if (SM == 1)
                    stf(&Cout[((size_t)(row >> 8) * N + col) * 256 + (row & 255)], v);
                else
                    stf(&Cout[(size_t)row * N + col], v);
            }
        }
}

// ---------------------------------------------------------------------------
// gv GEMM + fused sigmoid-weighted row reduction. AL zeroed before launch.
// ---------------------------------------------------------------------------
__global__ __launch_bounds__(256)
void gv_gemm_reduce(const bf16* __restrict__ A, const bf16* __restrict__ W,
                    const float* __restrict__ bv, const float* __restrict__ wv1,
                    float* __restrict__ al)
{
    __shared__ ushort Asm[128 * 40];
    __shared__ ushort Bsm[128 * 40];
    const int bm = blockIdx.y * 128, bn = blockIdx.x * 128;
    const int tid = threadIdx.x;
    const int lane = tid & 63, w = tid >> 6, wr = w >> 1, wc = w & 1;

    f32x4 acc[4][4] = {};
    for (int kt = 0; kt < 8; ++kt) {
        const int k0 = kt << 5;
#pragma unroll
        for (int u = 0; u < 2; ++u) {
            const int idx = tid + u * 256;
            const int m = idx >> 2, q = idx & 3;
            *(s16x8*)&Asm[m * 40 + q * 8] =
                *(const s16x8*)&A[(size_t)(bm + m) * 256 + k0 + q * 8];
            *(s16x8*)&Bsm[m * 40 + q * 8] =
                *(const s16x8*)&W[(size_t)(bn + m) * 256 + k0 + q * 8];
        }
        __syncthreads();
        s16x8 af[4], bfr[4];
#pragma unroll
        for (int t = 0; t < 4; ++t) {
            af[t]  = *(const s16x8*)&Asm[(wr * 64 + t * 16 + (lane & 15)) * 40 + (lane >> 4) * 8];
            bfr[t] = *(const s16x8*)&Bsm[(wc * 64 + t * 16 + (lane & 15)) * 40 + (lane >> 4) * 8];
        }
#pragma unroll
        for (int mf = 0; mf < 4; ++mf)
#pragma unroll
            for (int nf = 0; nf < 4; ++nf)
                acc[mf][nf] = __builtin_amdgcn_mfma_f32_16x16x32_bf16(
                    af[mf], bfr[nf], acc[mf][nf], 0, 0, 0);
        __syncthreads();
    }

    float bb[4], wv[4];
#pragma unroll
    for (int nf = 0; nf < 4; ++nf) {
        const int col = bn + wc * 64 + nf * 16 + (lane & 15);
        bb[nf] = bv[col];
        wv[nf] = wv1[col];
    }
    const size_t cbase = (size_t)(bn >> 8) * BLn;
#pragma unroll
    for (int mf = 0; mf < 4; ++mf)
#pragma unroll
        for (int i = 0; i < 4; ++i) {
            float p = 0.f;
#pragma unroll
            for (int nf = 0; nf < 4; ++nf)
                p += wv[nf] / (1.f + expf(-(acc[mf][nf][i] + bb[nf])));
            p += __shfl_xor(p, 1); p += __shfl_xor(p, 2);
            p += __shfl_xor(p, 4); p += __shfl_xor(p, 8);
            if ((lane & 15) == 0) {
                const int row = bm + wr * 64 + mf * 16 + (lane >> 4) * 4 + i;
                atomicAdd(&al[cbase + row], p);
            }
        }
}

// ---------------------------------------------------------------------------
// GRU scan v9 (settled floor: 266us). k-split over 768 threads (12 waves).
// LDS-throughput bound at ~92% of the 192-slot/step delivery limit; the
// register file (r5/6/9), L2 (r3), readlane (r10/13), and shfl-pairing
// (r15) alternatives all measured worse. Do not touch.
// ---------------------------------------------------------------------------
__global__ __launch_bounds__(768, 1)
void gru_scan_v9(const bf16* __restrict__ gx, const float* __restrict__ w_hh,
                 const float* __restrict__ b_hh, bf16* __restrict__ out)
{
    const int b = blockIdx.x, dir = blockIdx.y;
    const int t = threadIdx.x;
    const int half = t >= 384 ? 1 : 0;
    const int r = t - 384 * half;            // gate row 0..383
    __shared__ __align__(16) ushort wl[384 * 136];   // 272B rows, 104448 B
    __shared__ __align__(16) ushort hp16[128];       // h as f16
    __shared__ float h_sh[128];
    __shared__ float part[384];
    __shared__ float rs[128], zs[128], gxn[128], ghn[128];

    const float* wbase = w_hh + (size_t)dir * G3n * Hn;
    for (int idx = t; idx < G3n * 64; idx += 768) {
        const int row = idx >> 6, k2 = idx & 63;
        const float2 v = *(const float2*)(wbase + row * Hn + 2 * k2);
        h16x2 p; p[0] = (_Float16)v.x; p[1] = (_Float16)v.y;
        *(h16x2*)&wl[row * 136 + 2 * k2] = p;
    }
    if (t < 128) { hp16[t] = 0; h_sh[t] = 0.f; }
    const float bh = b_hh[dir * G3n + r];
    __syncthreads();

    const size_t g0 = (size_t)b * Ln * 768 + dir * G3n + r
                      + (dir ? (size_t)(Ln - 1) * 768 : 0);
    const long gstep = dir ? -768L : 768L;
    float gcur = 0.f, gnx = 0.f;
    if (!half) { gcur = ldf(&gx[g0]); gnx = ldf(&gx[g0 + gstep]); }

    const ushort* wrow  = &wl[r * 136 + half * 64];
    const ushort* hbase = &hp16[half * 64];

    for (int s = 0; s < Ln; ++s) {
        const int tt = dir ? (Ln - 1 - s) : s;
        float gn2 = 0.f;
        if (!half && s + 2 < Ln) gn2 = ldf(&gx[g0 + (long)(s + 2) * gstep]);

        float a0 = 0.f, a1 = 0.f, a2 = 0.f, a3 = 0.f;
#pragma unroll
        for (int j = 0; j < 8; ++j) {
            const float4 wv = *(const float4*)&wrow[8 * j];
            const float4 hv = *(const float4*)&hbase[8 * j];
            a0 = dot2f(BCH(wv.x), BCH(hv.x), a0);
            a1 = dot2f(BCH(wv.y), BCH(hv.y), a1);
            a2 = dot2f(BCH(wv.z), BCH(hv.z), a2);
            a3 = dot2f(BCH(wv.w), BCH(hv.w), a3);
        }
        const float acc = (a0 + a1) + (a2 + a3);
        if (half) part[r] = acc;
        __syncthreads();

        if (!half) {
            const float tot = acc + part[r] + bh;
            if (r < 128)      rs[r]       = 1.f / (1.f + expf(-(gcur + tot)));
            else if (r < 256) zs[r - 128] = 1.f / (1.f + expf(-(gcur + tot)));
            else { gxn[r - 256] = gcur; ghn[r - 256] = tot; }
        }
        __syncthreads();

        if (t < 128) {
            const int j = t;
            const float nn = tanhf(gxn[j] + rs[j] * ghn[j]);
            const float hnew = (1.f - zs[j]) * nn + zs[j] * h_sh[j];
            h_sh[j] = hnew;
            const _Float16 hf = (_Float16)hnew;
            hp16[j] = __builtin_bit_cast(ushort, hf);
            out[((size_t)b * Ln + tt) * Dn + dir * Hn + j] = __float2bfloat16(hnew);
        }
        __syncthreads();
        if (!half) { gcur = gnx; gnx = gn2; }
    }
}

// ---------------------------------------------------------------------------
// attn score, MFMA, fused channels: grid (2, B, C); mat row stride 1024.
// ---------------------------------------------------------------------------
__global__ __launch_bounds__(256)
void attn_score_mfma(const bf16* __restrict__ x, const bf16* __restrict__ matb,
                     const float* __restrict__ attb, float* __restrict__ sout)
{
    const int it = blockIdx.x, b = blockIdx.y, c = blockIdx.z;
    const bf16* A  = x + ((size_t)b * 256 + it * 128) * 256;
    const bf16* Bm = matb + (size_t)b * 256 * 1024 + c * 256;
    __shared__ ushort Xs[128 * 40];
    __shared__ ushort Ms[128 * 40];
    const int tid = threadIdx.x, lane = tid & 63, w = tid >> 6;
    const float bc = attb[c];
    float psum[2][4] = {};

    for (int jt = 0; jt < 2; ++jt) {
        f32x4 acc[2][8] = {};
        for (int kt = 0; kt < 8; ++kt) {
            const int k0 = kt << 5;
#pragma unroll
            for (int u = 0; u < 2; ++u) {
                const int idx = tid + u * 256;
                const int m = idx >> 2, q = idx & 3;
                *(s16x8*)&Xs[m * 40 + q * 8] =
                    *(const s16x8*)&A[(size_t)m * 256 + k0 + q * 8];
                *(s16x8*)&Ms[m * 40 + q * 8] =
                    *(const s16x8*)&Bm[(size_t)(jt * 128 + m) * 1024 + k0 + q * 8];
            }
            __syncthreads();
            s16x8 af[2], bfr[8];
#pragma unroll
            for (int t = 0; t < 2; ++t)
                af[t] = *(const s16x8*)&Xs[(w * 32 + t * 16 + (lane & 15)) * 40 + (lane >> 4) * 8];
#pragma unroll
            for (int t = 0; t < 8; ++t)
                bfr[t] = *(const s16x8*)&Ms[(t * 16 + (lane & 15)) * 40 + (lane >> 4) * 8];
#pragma unroll
            for (int mf = 0; mf < 2; ++mf)
#pragma unroll
                for (int nf = 0; nf < 8; ++nf)
                    acc[mf][nf] = __builtin_amdgcn_mfma_f32_16x16x32_bf16(
                        af[mf], bfr[nf], acc[mf][nf], 0, 0, 0);
            __syncthreads();
        }
#pragma unroll
        for (int mf = 0; mf < 2; ++mf)
#pragma unroll
            for (int nf = 0; nf < 8; ++nf)
#pragma unroll
                for (int i = 0; i < 4; ++i)
                    psum[mf][i] += tanhf(acc[mf][nf][i] + bc);
    }

#pragma unroll
    for (int mf = 0; mf < 2; ++mf)
#pragma unroll
        for (int i = 0; i < 4; ++i) {
            float v = psum[mf][i];
            v += __shfl_xor(v, 1); v += __shfl_xor(v, 2);
            v += __shfl_xor(v, 4); v += __shfl_xor(v, 8);
            if ((lane & 15) == 0)
                sout[(size_t)c * BLn + b * 256 + it * 128 + w * 32 + mf * 16 + (lane >> 4) * 4 + i] = v;
        }
}

// transpose 4 matrices of 256x256 (src[c][d][e] fp32 -> dst[c][e][d] bf16)
__global__ void transpose256(const float* __restrict__ src, bf16* __restrict__ dst)
{
    const float* s = src + (size_t)blockIdx.x * 65536;
    bf16* d = dst + (size_t)blockIdx.x * 65536;
    __shared__ float t[32][33];
    const int tx = threadIdx.x & 31, ty8 = threadIdx.x >> 5;
    for (int bi = 0; bi < 8; ++bi)
        for (int bj = 0; bj < 8; ++bj) {
            __syncthreads();
            for (int r = ty8; r < 32; r += 8)
                t[r][tx] = s[(size_t)(bi * 32 + r) * 256 + bj * 32 + tx];
            __syncthreads();
            for (int r = ty8; r < 32; r += 8)
                stf(&d[(size_t)(bj * 32 + r) * 256 + bi * 32 + tx], t[tx][r]);
        }
}

__global__ void softmax256(const float* __restrict__ in, float* __restrict__ out)
{
    __shared__ float red[256];
    const int row = blockIdx.x, t = threadIdx.x;
    const float v = in[(size_t)row * 256 + t];
    red[t] = v; __syncthreads();
    for (int off = 128; off; off >>= 1) {
        if (t < off) red[t] = fmaxf(red[t], red[t + off]);
        __syncthreads();
    }
    const float mx = red[0]; __syncthreads();
    const float e = expf(v - mx);
    red[t] = e; __syncthreads();
    for (int off = 128; off; off >>= 1) {
        if (t < off) red[t] += red[t + off];
        __syncthreads();
    }
    out[(size_t)row * 256 + t] = e / red[0];
}

// new[c,b,d] for all 4 c in one pass over x (x read once per b)
__global__ __launch_bounds__(256)
void weighted_sum_kernel(const float* __restrict__ aa,
                         const bf16* __restrict__ x,
                         float* __restrict__ outnew)
{
    const int b = blockIdx.x, d = threadIdx.x;
    __shared__ float w4[4][Ln];
    for (int i = d; i < 4 * Ln; i += 256)
        w4[i >> 8][i & 255] = aa[((size_t)(i >> 8) * Bn + b) * Ln + (i & 255)];
    __syncthreads();
    float a0 = 0.f, a1 = 0.f, a2 = 0.f, a3 = 0.f;
    for (int l = 0; l < Ln; ++l) {
        const float xv = ldf(&x[((size_t)b * Ln + l) * Dn + d]);
        a0 += w4[0][l] * xv; a1 += w4[1][l] * xv;
        a2 += w4[2][l] * xv; a3 += w4[3][l] * xv;
    }
    outnew[((size_t)0 * Bn + b) * Dn + d] = a0;
    outnew[((size_t)1 * Bn + b) * Dn + d] = a1;
    outnew[((size_t)2 * Bn + b) * Dn + d] = a2;
    outnew[((size_t)3 * Bn + b) * Dn + d] = a3;
}

// pack conv filter rows (216) into 256x256 fp32 (rows 216+ zero)
__global__ void wpack_fill(const float* __restrict__ w0, const float* __restrict__ w1,
                           const float* __restrict__ w2, const float* __restrict__ w3,
                           float* __restrict__ wp)
{
    const int f = blockIdx.x;
    if (f < 4) {
        const int cnt[4]  = {4096, 9216, 16384, 25600};
        const int boff[4] = {0, 4096, 13312, 29696};
        const float* src = f == 0 ? w0 : f == 1 ? w1 : f == 2 ? w2 : w3;
        for (int i = threadIdx.x; i < cnt[f]; i += blockDim.x)
            wp[boff[f] + i] = src[i];
    } else {
        for (int i = threadIdx.x; i < 65536 - 55296; i += blockDim.x)
            wp[55296 + i] = 0.f;
    }
}

// nwd[b,row] = dot(new[c_of_row, b, :], wpack[row, :])
__global__ __launch_bounds__(256)
void nwd_kernel(const float* __restrict__ nw, const float* __restrict__ wp,
                float* __restrict__ nwd)
{
    const int b = blockIdx.x;
    __shared__ float ns[4][256];
    for (int i = threadIdx.x; i < 1024; i += 256)
        ns[i >> 8][i & 255] = nw[((size_t)((i >> 8) * Bn + b) << 8) + (i & 255)];
    __syncthreads();
    const int row = threadIdx.x;
    if (row < 216) {
        int f, base;
        if (row < 16)       { f = 0; base = 0; }
        else if (row < 52)  { f = 1; base = 16; }
        else if (row < 116) { f = 2; base = 52; }
        else                { f = 3; base = 116; }
        const int fs = f + 2, local = row - base;
        const int c = (local / fs) & 3;
        const float* wr = wp + (size_t)row * 256;
        float acc = 0.f;
        for (int k = 0; k < 256; ++k) acc += ns[c][k] * wr[k];
        nwd[b * 256 + row] = acc;
    }
}

// conv+relu+maxpool, ALL 4 filter sizes in one launch: grid (B, 4).
__global__ __launch_bounds__(256)
void conv_combine_all(const bf16* __restrict__ xwT, const float* __restrict__ a,
                      const float* __restrict__ nwd,
                      const float* __restrict__ cb0, const float* __restrict__ cb1,
                      const float* __restrict__ cb2, const float* __restrict__ cb3,
                      float* __restrict__ pool)
{
    const int b = blockIdx.x, f = blockIdx.y, tid = threadIdx.x;
    const int fs = f + 2;
    const int base = (f == 0) ? 0 : (f == 1) ? 16 : (f == 2) ? 52 : 116;
    const int poff = (f == 0) ? 0 : (f == 1) ? 2 : (f == 2) ? 5 : 9;
    const float* cb = (f == 0) ? cb0 : (f == 1) ? cb1 : (f == 2) ? cb2 : cb3;

    __shared__ float ash[4][256];
    __shared__ float basev[5];
    __shared__ float red[256];
    for (int i = tid; i < 1024; i += 256)
        ash[i >> 8][i & 255] = a[((size_t)((i >> 8) * Bn + b) << 8) + (i & 255)];
    if (tid < fs) {
        float s = cb[tid];
        for (int c = 0; c < 4; ++c)
            for (int kh = 0; kh < fs; ++kh)
                s += nwd[b * 256 + base + (tid * 4 + c) * fs + kh];
        basev[tid] = s;
    }
    __syncthreads();
    const int ni = Ln - fs + 1;
    const bf16* xb = xwT + ((size_t)b << 16);
    for (int o = 0; o < fs; ++o) {
        float best = 0.f;
        if (tid < ni) {
            float acc = basev[o];
            for (int c = 0; c < 4; ++c)
                for (int kh = 0; kh < fs; ++kh) {
                    const int row = base + (o * 4 + c) * fs + kh;
                    acc += ash[c][tid + kh] * ldf(&xb[(row << 8) + tid + kh]);
                }
            best = fmaxf(acc, 0.f);
        }
        red[tid] = best; __syncthreads();
        for (int off = 128; off; off >>= 1) {
            if (tid < off) red[tid] = fmaxf(red[tid], red[tid + off]);
            __syncthreads();
        }
        if (tid == 0) pool[b * 14 + poff + o] = red[0];
        __syncthreads();
    }
}

__global__ void fc_kernel(const float* __restrict__ pool, const float* __restrict__ fw,
                          const float* __restrict__ fb, float* __restrict__ out)
{
    const int i = threadIdx.x;           // 256 = B*OUT
    const int b = i >> 1, o = i & 1;
    float acc = fb[o];
#pragma unroll
    for (int f = 0; f < 14; ++f) acc += pool[b * 14 + f] * fw[o * 14 + f];
    out[i] = acc;
}

// ---------------------------------------------------------------------------
extern "C" void kernel_launch(void* const* d_in, const int* in_sizes, int n_in,
                              void* d_out, int out_size, void* d_ws, size_t ws_size,
                              hipStream_t stream)
{
    const int*   utt    = (const int*)  d_in[0];
    const float* emb    = (const float*)d_in[2];
    const float* w_ih0  = (const float*)d_in[3];
    const float* w_hh0  = (const float*)d_in[4];
    const float* b_ih0  = (const float*)d_in[5];
    const float* b_hh0  = (const float*)d_in[6];
    const float* w_ih1  = (const float*)d_in[7];
    const float* w_hh1  = (const float*)d_in[8];
    const float* b_ih1  = (const float*)d_in[9];
    const float* b_hh1  = (const float*)d_in[10];
    const float* att_w  = (const float*)d_in[11];
    const float* att_b  = (const float*)d_in[12];
    const float* att_wv2= (const float*)d_in[13];
    const float* att_bv = (const float*)d_in[14];
    const float* att_wv1= (const float*)d_in[15];
    const float* fc_w   = (const float*)d_in[16];
    const float* fc_b   = (const float*)d_in[17];
    const float* cw[4] = {(const float*)d_in[18], (const float*)d_in[20],
                          (const float*)d_in[22], (const float*)d_in[24]};
    const float* cb[4] = {(const float*)d_in[19], (const float*)d_in[21],
                          (const float*)d_in[23], (const float*)d_in[25]};

    float* ws = (float*)d_ws;
    bf16*  GX   = (bf16*)ws;                          // [0, 12.58M f32)
    bf16*  H1   = (bf16*)(ws + 12582912);             // [12.58M, 16.78M)
    bf16*  H2   = (bf16*)(ws + 16777216);             // [16.78M, 20.97M)
    bf16*  WT   = (bf16*)(ws + 20971520);             //   131,072 f32 slots
    float* WP   = ws + 20971520 + 131072;             //    65,536 f
    float* S    = WP + 65536;                         //   131,072 f
    float* Aa   = S + 131072;
    float* AL   = Aa + 131072;
    float* AAa  = AL + 131072;
    float* NEW_ = AAa + 131072;
    float* NWD  = NEW_ + 131072;                      //    32,768 f
    float* POOL = NWD + 32768;                        //     1,792 f
    bf16*  MATB = (bf16*)ws;   // fused-channel MAT, 67MB over dead GX+H1
    bf16*  XWT  = (bf16*)ws;   // bf16 xw output (16.7MB), aliases dead region

    // layer 0 + scan
    gemm_mfma<float, float, bf16, true, 0><<<dim3(6, 256), 256, 0, stream>>>(
        emb, w_ih0, b_ih0, GX, utt, BLn, 768, En);
    gru_scan_v9<<<dim3(Bn, 2), 768, 0, stream>>>(GX, w_hh0, b_hh0, H1);
    // layer 1 + scan
    gemm_mfma<bf16, float, bf16, false, 0><<<dim3(6, 256), 256, 0, stream>>>(
        H1, w_ih1, b_ih1, GX, nullptr, BLn, 768, Dn);
    gru_scan_v9<<<dim3(Bn, 2), 768, 0, stream>>>(GX, w_hh1, b_hh1, H2);

    // scalar attention: MATB = x @ [att_w^T stacked], fused 4-channel scores
    transpose256<<<4, 256, 0, stream>>>(att_w, WT);
    gemm_mfma<bf16, bf16, bf16, false, 0><<<dim3(8, 256), 256, 0, stream>>>(
        H2, WT, nullptr, MATB, nullptr, BLn, 1024, Dn);
    attn_score_mfma<<<dim3(2, Bn, Cn), 256, 0, stream>>>(H2, MATB, att_b, S);
    softmax256<<<Cn * Bn, 256, 0, stream>>>(S, Aa);

    // vector attention: fused GEMM+reduce (no gv materialization)
    transpose256<<<4, 256, 0, stream>>>(att_wv2, WT);
    hipMemsetAsync(AL, 0, (size_t)Cn * BLn * sizeof(float), stream);
    gv_gemm_reduce<<<dim3(8, 256), 256, 0, stream>>>(H2, WT, att_bv, att_wv1, AL);
    softmax256<<<Cn * Bn, 256, 0, stream>>>(AL, AAa);
    weighted_sum_kernel<<<Bn, 256, 0, stream>>>(AAa, H2, NEW_);

    // conv stage via xw GEMM decomposition (Cf never materialized)
    wpack_fill<<<5, 256, 0, stream>>>(cw[0], cw[1], cw[2], cw[3], WP);
    gemm_mfma<bf16, float, bf16, false, 1><<<dim3(2, 256), 256, 0, stream>>>(
        H2, WP, nullptr, XWT, nullptr, BLn, Dn, Dn);
    nwd_kernel<<<Bn, 256, 0, stream>>>(NEW_, WP, NWD);

    conv_combine_all<<<dim3(Bn, 4), 256, 0, stream>>>(
        XWT, Aa, NWD, cb[0], cb[1], cb[2], cb[3], POOL);

    fc_kernel<<<1, 256, 0, stream>>>(POOL, fc_w, fc_b, (float*)d_out);
}